// Round 21
// baseline (219.313 us; speedup 1.0000x reference)
//
#include <hip/hip_runtime.h>

typedef short bf16x8 __attribute__((ext_vector_type(8)));
typedef float f32x4 __attribute__((ext_vector_type(4)));

#define LN_EPS 1e-6f
#define QSCALE 0.1803368801111143f   // 0.125 * log2(e)

static __device__ __forceinline__ float bf2f(unsigned short u) {
    union { unsigned int i; float f; } v; v.i = ((unsigned int)u) << 16; return v.f;
}
static __device__ __forceinline__ unsigned short f2bf(float f) {
    union { float ff; unsigned int i; } v; v.ff = f;
    return (unsigned short)((v.i + 0x7FFFu + ((v.i >> 16) & 1u)) >> 16);  // RNE
}
// async global->LDS, 16B per lane; LDS dest is wave-uniform base + lane*16
static __device__ __forceinline__ void gl_lds16(const unsigned short* g, unsigned short* l) {
    __builtin_amdgcn_global_load_lds((__attribute__((address_space(1))) void*)g,
                                     (__attribute__((address_space(3))) void*)l,
                                     16, 0, 0);
}

// ---------------- kernel: fused prep = {transpose w_qkv, transpose w_out, mod} ----------------
// blocks 0..3071: transpose w_qkv; 3072..4095: transpose w_out; 4096..4863: mod (K-split x8).
__global__ __launch_bounds__(256) void prep_kernel(const float* __restrict__ w_qkv,
                                                   unsigned short* __restrict__ wqkvT,
                                                   const float* __restrict__ w_out,
                                                   unsigned short* __restrict__ woutT,
                                                   const float* __restrict__ timep,
                                                   const float* __restrict__ mod_w,
                                                   const float* __restrict__ mod_b,
                                                   float* __restrict__ mod) {
    __shared__ __align__(16) char sm[5248];
    const int bid = blockIdx.x;
    if (bid < 4096) {
        const float* src; unsigned short* dst; int C, c0, r0;
        if (bid < 3072) { src = w_qkv; dst = wqkvT; C = 3072; c0 = (bid % 96) * 32; r0 = (bid / 96) * 32; }
        else { int i2 = bid - 3072; src = w_out; dst = woutT; C = 1024; c0 = (i2 & 31) * 32; r0 = (i2 >> 5) * 32; }
        unsigned short (*t)[33] = (unsigned short(*)[33])sm;
        int tx = threadIdx.x & 31, ty = threadIdx.x >> 5;
        #pragma unroll
        for (int i = 0; i < 4; ++i) {
            int r = ty + i * 8;
            t[r][tx] = f2bf(src[(size_t)(r0 + r) * C + c0 + tx]);
        }
        __syncthreads();
        #pragma unroll
        for (int i = 0; i < 4; ++i) {
            int c = ty + i * 8;
            dst[(size_t)(c0 + c) * 1024 + r0 + tx] = t[tx][c];
        }
    } else {
        const int mb = bid - 4096;                // 0..767
        float* st = (float*)sm;                   // 4096 B
        float (*part)[33] = (float(*)[33])(sm + 4096);
        const int b = mb / 96;
        const int jb = mb % 96;
        const int tid = threadIdx.x;
        const int j = jb * 32 + (tid & 31);
        const int sub = tid >> 5;                 // 0..7, covers k = sub*128..+127
        for (int i = tid; i < 1024; i += 256) {
            float t = timep[b * 1024 + i];
            st[i] = t / (1.0f + __expf(-t));      // silu
        }
        __syncthreads();
        float acc = 0.f;
        const int k0 = sub * 128;
        #pragma unroll 4
        for (int m = 0; m < 128; ++m)
            acc = fmaf(st[k0 + m], mod_w[(size_t)(k0 + m) * 3072 + j], acc);
        part[sub][tid & 31] = acc;
        __syncthreads();
        if (tid < 32) {
            float s = mod_b[jb * 32 + tid];
            #pragma unroll
            for (int p = 0; p < 8; ++p) s += part[p][tid];   // fixed order: deterministic
            mod[b * 3072 + jb * 32 + tid] = s;
        }
    }
}

// ---------------- kernel: h = LN(x) * (scale+1) + shift -> bf16; wave-per-row, no LDS/barriers ----------------
__global__ __launch_bounds__(256) void ln_mod_kernel(const float* __restrict__ x,
                                                     const float* __restrict__ mod,
                                                     unsigned short* __restrict__ h) {
    int row = blockIdx.x * 4 + (threadIdx.x >> 6);   // b*1024 + t
    int lane = threadIdx.x & 63;
    int b = row >> 10;
    const float* xr = x + (size_t)row * 1024;
    float4 v[4];
    float s = 0.f, ss = 0.f;
    #pragma unroll
    for (int j = 0; j < 4; ++j) {
        v[j] = *reinterpret_cast<const float4*>(xr + j * 256 + lane * 4);
        s  += v[j].x + v[j].y + v[j].z + v[j].w;
        ss += v[j].x * v[j].x + v[j].y * v[j].y + v[j].z * v[j].z + v[j].w * v[j].w;
    }
    #pragma unroll
    for (int o = 32; o >= 1; o >>= 1) { s += __shfl_xor(s, o); ss += __shfl_xor(ss, o); }
    float mean = s * (1.0f / 1024.0f);
    float rstd = rsqrtf(ss * (1.0f / 1024.0f) - mean * mean + LN_EPS);
    const float* mb = mod + b * 3072;
    #pragma unroll
    for (int j = 0; j < 4; ++j) {
        int d = j * 256 + lane * 4;
        float4 shf = *reinterpret_cast<const float4*>(mb + d);          // shift
        float4 scl = *reinterpret_cast<const float4*>(mb + 1024 + d);   // scale
        ushort4 o4;
        o4.x = f2bf((v[j].x - mean) * rstd * (scl.x + 1.0f) + shf.x);
        o4.y = f2bf((v[j].y - mean) * rstd * (scl.y + 1.0f) + shf.y);
        o4.z = f2bf((v[j].z - mean) * rstd * (scl.z + 1.0f) + shf.z);
        o4.w = f2bf((v[j].w - mean) * rstd * (scl.w + 1.0f) + shf.w);
        *reinterpret_cast<ushort4*>(h + (size_t)row * 1024 + d) = o4;
    }
}

// ---------------- MFMA GEMM main loop (m97 structure): global_load_lds staging ----------------
static __device__ __forceinline__ void gemm_mainloop(const unsigned short* __restrict__ A,
                                                     const unsigned short* __restrict__ Bt,
                                                     int m0, int n0,
                                                     unsigned short* As, unsigned short* Bs,
                                                     f32x4 (&acc)[4][4]) {
    const int tid = threadIdx.x;
    const int wid = tid >> 6, lane = tid & 63;
    const int wr = wid >> 1, wc = wid & 1;
    const int lr = lane & 15, lks = lane >> 4;
    const int gofs = (lane >> 3) * 1024 + (((lane & 7) ^ (lane >> 3)) * 8);
    const unsigned short* Ag = A  + (size_t)(m0 + wid * 32) * 1024 + gofs;
    const unsigned short* Bg = Bt + (size_t)(n0 + wid * 32) * 1024 + gofs;
    unsigned short* AsW = As + wid * 32 * 64;
    unsigned short* BsW = Bs + wid * 32 * 64;
    for (int k0 = 0; k0 < 1024; k0 += 64) {
        __syncthreads();
        #pragma unroll
        for (int j = 0; j < 4; ++j) {
            gl_lds16(Ag + k0 + j * 8192, AsW + j * 512);
            gl_lds16(Bg + k0 + j * 8192, BsW + j * 512);
        }
        __syncthreads();
        #pragma unroll
        for (int ks = 0; ks < 2; ++ks) {
            bf16x8 af[4], bfr[4];
            #pragma unroll
            for (int mi = 0; mi < 4; ++mi) {
                int row = wr * 64 + mi * 16 + lr;
                int ss = (ks * 4 + lks) ^ (row & 7);
                af[mi] = *reinterpret_cast<const bf16x8*>(As + row * 64 + ss * 8);
            }
            #pragma unroll
            for (int ni = 0; ni < 4; ++ni) {
                int row = wc * 64 + ni * 16 + lr;
                int ss = (ks * 4 + lks) ^ (row & 7);
                bfr[ni] = *reinterpret_cast<const bf16x8*>(Bs + row * 64 + ss * 8);
            }
            #pragma unroll
            for (int mi = 0; mi < 4; ++mi)
                #pragma unroll
                for (int ni = 0; ni < 4; ++ni)
                    acc[mi][ni] = __builtin_amdgcn_mfma_f32_16x16x32_bf16(af[mi], bfr[ni], acc[mi][ni], 0, 0, 0);
        }
    }
}

// ---------------- kernel: qkv GEMM (MFMA); q/k scattered (B,H,T,64); v stored TRANSPOSED (B,H,64,T) ----------------
// boff splits the 1536-block grid into balanced 768-block launches (3 blocks/CU exactly).
__global__ __launch_bounds__(256) void gemm_qkv_mfma(const unsigned short* __restrict__ A,
                                                     const unsigned short* __restrict__ Bt,
                                                     unsigned short* __restrict__ qb,
                                                     unsigned short* __restrict__ kb,
                                                     unsigned short* __restrict__ vb,
                                                     int boff) {
    __shared__ __align__(16) unsigned short smem[16640];   // As|Bs (16384), bounce uses stride 130
    unsigned short* As = smem;
    unsigned short* Bs = smem + 8192;
    const int bid = blockIdx.y * 24 + blockIdx.x + boff;
    const int xcd = bid & 7, idx = bid >> 3;
    const int m0 = (xcd * 8 + (idx & 7)) * 128;
    const int n0 = (idx >> 3) * 128;
    const int tid = threadIdx.x;
    const int wid = tid >> 6, lane = tid & 63;
    const int wr = wid >> 1, wc = wid & 1;
    const int lr = lane & 15, g = lane >> 4;
    const int which = n0 >> 10;                     // block-uniform: 0=q 1=k 2=v
    f32x4 acc[4][4] = {};
    gemm_mainloop(A, Bt, m0, n0, As, Bs, acc);
    __syncthreads();
    // ---- bounce C tile to LDS (stride 130); v blocks bounce TRANSPOSED ----
    #pragma unroll
    for (int mi = 0; mi < 4; ++mi)
    #pragma unroll
    for (int ni = 0; ni < 4; ++ni)
    #pragma unroll
    for (int r = 0; r < 4; ++r) {
        int row = wr * 64 + mi * 16 + g * 4 + r;
        int col = wc * 64 + ni * 16 + lr;
        if (which == 2) smem[col * 130 + row] = f2bf(acc[mi][ni][r]);
        else            smem[row * 130 + col] = f2bf(acc[mi][ni][r]);
    }
    __syncthreads();
    const int bb = m0 >> 10, tbase = m0 & 1023;
    if (which == 2) {
        // transposed store: 16B along t
        #pragma unroll
        for (int p = 0; p < 8; ++p) {
            int seg = (tid >> 3) + p * 32;          // 0..255
            int erow = seg >> 1, half = seg & 1, sub = tid & 7;
            int4 v = *reinterpret_cast<const int4*>(smem + erow * 130 + half * 64 + sub * 8);
            int eg = (n0 & 1023) + erow;
            int hd = eg >> 6, ei = eg & 63;
            *reinterpret_cast<int4*>(vb + (((size_t)(bb * 16 + hd) * 64 + ei) << 10)
                                        + tbase + half * 64 + sub * 8) = v;
        }
    } else {
        unsigned short* dst = which == 0 ? qb : kb;
        #pragma unroll
        for (int p = 0; p < 8; ++p) {
            int seg = (tid >> 3) + p * 32;
            int row = seg >> 1, half = seg & 1, sub = tid & 7;
            int4 v = *reinterpret_cast<const int4*>(smem + row * 130 + half * 64 + sub * 8);
            int colb = n0 + half * 64;
            int hd = (colb & 1023) >> 6;
            int t = tbase + row;
            *reinterpret_cast<int4*>(dst + (((size_t)(bb * 16 + hd) * 1024 + t) << 6) + sub * 8) = v;
        }
    }
}

// ---------------- kernel: out GEMM (MFMA), 2-pass f32 LDS-bounce, fused gate ----------------
__global__ __launch_bounds__(256) void gemm_out_mfma(const unsigned short* __restrict__ A,
                                                     const unsigned short* __restrict__ Bt,
                                                     const float* __restrict__ mod,
                                                     float* __restrict__ out) {
    __shared__ __align__(16) unsigned short smem[16640];
    unsigned short* As = smem;
    unsigned short* Bs = smem + 8192;
    float* fsm = reinterpret_cast<float*>(smem);           // [64][128] f32 = 32 KB
    const int bid = blockIdx.y * 8 + blockIdx.x;
    const int xcd = bid & 7, idx = bid >> 3;
    const int m0 = (xcd * 8 + (idx & 7)) * 128;
    const int n0 = (idx >> 3) * 128;
    const int tid = threadIdx.x;
    const int wid = tid >> 6, lane = tid & 63;
    const int wr = wid >> 1, wc = wid & 1;
    const int lr = lane & 15, g = lane >> 4;
    f32x4 acc[4][4] = {};
    gemm_mainloop(A, Bt, m0, n0, As, Bs, acc);
    #pragma unroll
    for (int hp = 0; hp < 2; ++hp) {
        __syncthreads();
        if (wr == hp) {
            #pragma unroll
            for (int mi = 0; mi < 4; ++mi)
            #pragma unroll
            for (int ni = 0; ni < 4; ++ni)
            #pragma unroll
            for (int r = 0; r < 4; ++r)
                fsm[(mi * 16 + g * 4 + r) * 128 + wc * 64 + ni * 16 + lr] = acc[mi][ni][r];
        }
        __syncthreads();
        #pragma unroll
        for (int p = 0; p < 8; ++p) {
            int unit = tid + p * 256;
            int lrow = unit >> 5, sub = unit & 31;
            float4 v = *reinterpret_cast<const float4*>(fsm + lrow * 128 + sub * 4);
            int row = m0 + hp * 64 + lrow;
            int col = n0 + sub * 4;
            int bb = row >> 10;
            float4 gv = *reinterpret_cast<const float4*>(mod + bb * 3072 + 2048 + col);
            float4 o4;
            o4.x = v.x * gv.x; o4.y = v.y * gv.y; o4.z = v.z * gv.z; o4.w = v.w * gv.w;
            *reinterpret_cast<float4*>(out + (size_t)row * 1024 + col) = o4;
        }
    }
}

// ---------------- kernel: per-row (e=64) LN + RoPE, 4 rows/wave vectorized ----------------
__global__ __launch_bounds__(256) void lnrope_kernel(unsigned short* __restrict__ qb,
                                                     unsigned short* __restrict__ kb,
                                                     const float* __restrict__ qw,
                                                     const float* __restrict__ kw,
                                                     const float* __restrict__ pos) {
    int gw = blockIdx.x * 4 + (threadIdx.x >> 6);   // wave id 0..65535
    int lane = threadIdx.x & 63;
    int half = gw >> 15;                            // 0 = q, 1 = k
    int rw = (gw * 4 + (lane >> 4)) & 131071;       // row within buffer
    unsigned short* buf = half ? kb : qb;
    const float* w = half ? kw : qw;
    int t = rw & 1023;
    int c4 = (lane & 15) * 4;                       // element base 0..60
    size_t idx = (size_t)rw * 64 + c4;
    ushort4 u = *reinterpret_cast<const ushort4*>(buf + idx);
    float f0 = bf2f(u.x), f1 = bf2f(u.y), f2 = bf2f(u.z), f3 = bf2f(u.w);
    float s1 = f0 + f1 + f2 + f3;
    float s2 = f0 * f0 + f1 * f1 + f2 * f2 + f3 * f3;
    #pragma unroll
    for (int o = 1; o <= 8; o <<= 1) { s1 += __shfl_xor(s1, o); s2 += __shfl_xor(s2, o); }
    float mean = s1 * (1.0f / 64.0f);
    float rstd = rsqrtf(s2 * (1.0f / 64.0f) - mean * mean + LN_EPS);
    float4 wv = *reinterpret_cast<const float4*>(w + c4);
    float y0 = (f0 - mean) * rstd * wv.x;
    float y1 = (f1 - mean) * rstd * wv.y;
    float y2 = (f2 - mean) * rstd * wv.z;
    float y3 = (f3 - mean) * rstd * wv.w;
    if (c4 < 32) {   // rotated half; pairs (y0,y1),(y2,y3) in-lane
        float4 p = *reinterpret_cast<const float4*>(pos + t * 32 + c4);
        float a;
        a = y0; y0 = a * p.x - y1 * p.y; y1 = y1 * p.x + a * p.y;
        a = y2; y2 = a * p.z - y3 * p.w; y3 = y3 * p.z + a * p.w;
    }
    const float SC = half ? 1.0f : QSCALE;          // q: fold 1/8 and log2e (softmax uses exp2)
    ushort4 o;
    o.x = f2bf(y0 * SC); o.y = f2bf(y1 * SC); o.z = f2bf(y2 * SC); o.w = f2bf(y3 * SC);
    *reinterpret_cast<ushort4*>(buf + idx) = o;
}

// ---------------- kernel: MFMA flash attention (R19 form) ----------------
// KVBLK=64, no-max exp2 softmax, double-buffered K/V via global_load_lds,
// 40 KB LDS -> 4 blocks/CU; precomputed swizzled offsets; lane-partial l (VALU).
__global__ __launch_bounds__(256) void attn_mfma_kernel(const unsigned short* __restrict__ qb,
                                                        const unsigned short* __restrict__ kb,
                                                        const unsigned short* __restrict__ vt,
                                                        unsigned short* __restrict__ ob) {
    __shared__ __align__(16) unsigned char smem[40960];
    unsigned short* KsB = (unsigned short*)smem;            // 2 x [64 kv][64 d]   (2 x 8 KB)
    unsigned short* VsB = (unsigned short*)(smem + 16384);  // 2 x [64 d][64 kv]   (2 x 8 KB)
    unsigned short* paQ = (unsigned short*)(smem + 32768);  // Q stage (8 KB), then pa[4][16][64] (8 KB)

    const int bid = blockIdx.x;
    const int swz = (bid & 7) * 256 + (bid >> 3);           // XCD-chunked
    const int bh = swz >> 4;
    const int q0 = (swz & 15) * 64;
    const int b = bh >> 4, hd = bh & 15;
    const size_t base = (size_t)bh << 16;                   // bh * 1024 * 64
    const int tid = threadIdx.x, wid = tid >> 6, lane = tid & 63;
    const int lr = lane & 15, g = lane >> 4;

    // ---- precomputed swizzled LDS offsets (loop-invariant; live in VGPRs) ----
    int kRd[2][4], pRd[2], pwOff[4][4];
    #pragma unroll
    for (int ks = 0; ks < 2; ++ks) {
        pRd[ks] = lr * 64 + (((ks * 4 + g) ^ (lr & 7)) * 8);
        #pragma unroll
        for (int nt = 0; nt < 4; ++nt)
            kRd[ks][nt] = (nt * 16 + lr) * 64 + (((ks * 4 + g) ^ (lr & 7)) * 8);
    }
    #pragma unroll
    for (int nt = 0; nt < 4; ++nt)
    #pragma unroll
    for (int r = 0; r < 4; ++r) {
        int q = g * 4 + r;
        pwOff[nt][r] = q * 64 + (((nt * 2 + (lr >> 3)) ^ (q & 7)) * 8) + (lr & 7);
    }

    // per-lane pre-swizzled global source pointers for K/V staging
    const unsigned short* kSrc[2];
    const unsigned short* vSrc[2];
    #pragma unroll
    for (int p = 0; p < 2; ++p) {
        int idx = p * 256 + tid;
        int r = idx >> 3, sg = idx & 7;
        kSrc[p] = kb + base + (size_t)r * 64 + ((sg ^ (r & 7)) * 8);
        vSrc[p] = vt + base + (size_t)r * 1024 + ((sg ^ (r & 7)) * 8);
    }

    // ---- prologue: stage chunk 0 (buf 0) + stage Q ----
    #pragma unroll
    for (int p = 0; p < 2; ++p) {
        gl_lds16(kSrc[p], KsB + p * 2048 + wid * 512);
        gl_lds16(vSrc[p], VsB + p * 2048 + wid * 512);
    }
    #pragma unroll
    for (int p = 0; p < 2; ++p) {
        int r = (tid >> 3) + p * 32;
        int sseg = tid & 7;
        int4 qv = *reinterpret_cast<const int4*>(qb + base + (size_t)(q0 + r) * 64 + sseg * 8);
        *reinterpret_cast<int4*>(paQ + r * 64 + ((sseg ^ (r & 7)) * 8)) = qv;
    }
    __syncthreads();
    bf16x8 af[2];
    #pragma unroll
    for (int ks = 0; ks < 2; ++ks) {
        int row = wid * 16 + lr;
        af[ks] = *reinterpret_cast<const bf16x8*>(paQ + row * 64 + (((ks * 4 + g) ^ (row & 7)) * 8));
    }
    __syncthreads();   // af extraction done before any pa write

    f32x4 acc[4] = {};
    float l_par[4] = {0.f, 0.f, 0.f, 0.f};     // lane-partial denominators
    unsigned short* pa_w = paQ + wid * 1024;   // wave-private P [16 q][64 kv] swizzled
    const f32x4 zero4 = {0.f, 0.f, 0.f, 0.f};

    for (int cc = 0; cc < 16; ++cc) {
        const int cur = cc & 1;
        // ---- issue async prefetch of chunk cc+1 into the other buffer ----
        if (cc < 15) {
            const int kv1 = (cc + 1) * 64;
            unsigned short* Kd = KsB + (cur ^ 1) * 4096;
            unsigned short* Vd = VsB + (cur ^ 1) * 4096;
            #pragma unroll
            for (int p = 0; p < 2; ++p) {
                gl_lds16(kSrc[p] + (size_t)kv1 * 64, Kd + p * 2048 + wid * 512);
                gl_lds16(vSrc[p] + kv1,              Vd + p * 2048 + wid * 512);
            }
        }
        const unsigned short* Kc = KsB + cur * 4096;
        const unsigned short* Vc = VsB + cur * 4096;
        // ---- QK^T: S[16 q][64 kv] per wave (8 MFMAs); first ks uses C=0 ----
        f32x4 s[4];
        __builtin_amdgcn_s_setprio(1);
        #pragma unroll
        for (int nt = 0; nt < 4; ++nt) {
            bf16x8 kf = *reinterpret_cast<const bf16x8*>(Kc + kRd[0][nt]);
            s[nt] = __builtin_amdgcn_mfma_f32_16x16x32_bf16(af[0], kf, zero4, 0, 0, 0);
        }
        #pragma unroll
        for (int nt = 0; nt < 4; ++nt) {
            bf16x8 kf = *reinterpret_cast<const bf16x8*>(Kc + kRd[1][nt]);
            s[nt] = __builtin_amdgcn_mfma_f32_16x16x32_bf16(af[1], kf, s[nt], 0, 0, 0);
        }
        __builtin_amdgcn_s_setprio(0);
        // ---- no-max softmax: P = exp2(s), lane-partial l ----
        #pragma unroll
        for (int r = 0; r < 4; ++r)
        #pragma unroll
        for (int nt = 0; nt < 4; ++nt) {
            float e = exp2f(s[nt][r]);
            s[nt][r] = e;
            l_par[r] += e;
        }
        // ---- write P (bf16) to wave-private LDS in A-fragment layout ----
        #pragma unroll
        for (int nt = 0; nt < 4; ++nt)
        #pragma unroll
        for (int r = 0; r < 4; ++r) {
            unsigned int pk;
            asm("v_cvt_pk_bf16_f32 %0, %1, %2" : "=v"(pk) : "v"(s[nt][r]), "v"(0.f));
            pa_w[pwOff[nt][r]] = (unsigned short)pk;
        }
        // ---- PV: O += P @ V (8 MFMAs) ----
        __builtin_amdgcn_s_setprio(1);
        #pragma unroll
        for (int ks = 0; ks < 2; ++ks) {
            bf16x8 paf = *reinterpret_cast<const bf16x8*>(pa_w + pRd[ks]);
            #pragma unroll
            for (int nt = 0; nt < 4; ++nt) {
                bf16x8 vf = *reinterpret_cast<const bf16x8*>(Vc + kRd[ks][nt]);
                acc[nt] = __builtin_amdgcn_mfma_f32_16x16x32_bf16(paf, vf, acc[nt], 0, 0, 0);
            }
        }
        __builtin_amdgcn_s_setprio(0);
        // one barrier: all reads of buf[cur] done (next iter overwrites it) AND
        // drains vmcnt so the cc+1 prefetch is visible for the next iteration.
        __syncthreads();
    }
    // ---- final: reduce lane-partial l, O/l, write (B, T, H*64) ----
    float inv[4];
    #pragma unroll
    for (int r = 0; r < 4; ++r) {
        float l = l_par[r];
        #pragma unroll
        for (int o = 1; o <= 8; o <<= 1) l += __shfl_xor(l, o);
        inv[r] = 1.0f / l;
    }
    #pragma unroll
    for (int nt = 0; nt < 4; ++nt)
    #pragma unroll
    for (int r = 0; r < 4; ++r) {
        int q = q0 + wid * 16 + g * 4 + r;
        int d = hd * 64 + nt * 16 + lr;
        ob[(size_t)(b * 1024 + q) * 1024 + d] = f2bf(acc[nt][r] * inv[r]);
    }
}

extern "C" void kernel_launch(void* const* d_in, const int* in_sizes, int n_in,
                              void* d_out, int out_size, void* d_ws, size_t ws_size,
                              hipStream_t stream) {
    const float* x      = (const float*)d_in[0];
    const float* timep  = (const float*)d_in[1];
    const float* pos    = (const float*)d_in[2];
    const float* mod_w  = (const float*)d_in[3];
    const float* mod_b  = (const float*)d_in[4];
    const float* w_qkv  = (const float*)d_in[5];
    const float* w_out  = (const float*)d_in[6];
    const float* qw     = (const float*)d_in[7];
    const float* kw     = (const float*)d_in[8];
    float* outp = (float*)d_out;                   // f32 (8,1024,1024)

    char* ws = (char*)d_ws;
    float*          modbuf = (float*)ws;                          // 98304 B
    unsigned short* wqkvT  = (unsigned short*)(ws + 98304);       // bf16 [3072][1024]
    unsigned short* woutT  = (unsigned short*)(ws + 6389760);     // bf16 [1024][1024]
    unsigned short* hbuf   = (unsigned short*)(ws + 8486912);     // 16 MB (h, then o)
    unsigned short* qbuf   = hbuf + 8388608;
    unsigned short* kbuf   = qbuf + 8388608;
    unsigned short* vbuf   = kbuf + 8388608;       // v in (B,H,64,T) layout
    unsigned short* obuf   = hbuf;

    prep_kernel<<<4864, 256, 0, stream>>>(w_qkv, wqkvT, w_out, woutT, timep, mod_w, mod_b, modbuf);
    ln_mod_kernel<<<2048, 256, 0, stream>>>(x, modbuf, hbuf);
    // split into two 768-block launches: 3 blocks/CU each, no imbalanced tail cohort
    gemm_qkv_mfma<<<dim3(24, 32), 256, 0, stream>>>(hbuf, wqkvT, qbuf, kbuf, vbuf, 0);
    gemm_qkv_mfma<<<dim3(24, 32), 256, 0, stream>>>(hbuf, wqkvT, qbuf, kbuf, vbuf, 768);
    lnrope_kernel<<<16384, 256, 0, stream>>>(qbuf, kbuf, qw, kw, pos);
    attn_mfma_kernel<<<2048, 256, 0, stream>>>(qbuf, kbuf, vbuf, obuf);
    gemm_out_mfma<<<dim3(8, 64), 256, 0, stream>>>(obuf, woutT, modbuf, outp);
}

// Round 22
// 199.324 us; speedup vs baseline: 1.1003x; 1.1003x over previous
//
#include <hip/hip_runtime.h>

typedef short bf16x8 __attribute__((ext_vector_type(8)));
typedef float f32x4 __attribute__((ext_vector_type(4)));

#define LN_EPS 1e-6f
#define QSCALE 0.1803368801111143f   // 0.125 * log2(e)

static __device__ __forceinline__ float bf2f(unsigned short u) {
    union { unsigned int i; float f; } v; v.i = ((unsigned int)u) << 16; return v.f;
}
static __device__ __forceinline__ unsigned short f2bf(float f) {
    union { float ff; unsigned int i; } v; v.ff = f;
    return (unsigned short)((v.i + 0x7FFFu + ((v.i >> 16) & 1u)) >> 16);  // RNE
}
// async global->LDS, 16B per lane; LDS dest is wave-uniform base + lane*16
static __device__ __forceinline__ void gl_lds16(const unsigned short* g, unsigned short* l) {
    __builtin_amdgcn_global_load_lds((__attribute__((address_space(1))) void*)g,
                                     (__attribute__((address_space(3))) void*)l,
                                     16, 0, 0);
}

// ---------------- kernel: fused prep = {transpose w_qkv, transpose w_out, mod} ----------------
// blocks 0..3071: transpose w_qkv; 3072..4095: transpose w_out; 4096..4863: mod (K-split x8).
__global__ __launch_bounds__(256) void prep_kernel(const float* __restrict__ w_qkv,
                                                   unsigned short* __restrict__ wqkvT,
                                                   const float* __restrict__ w_out,
                                                   unsigned short* __restrict__ woutT,
                                                   const float* __restrict__ timep,
                                                   const float* __restrict__ mod_w,
                                                   const float* __restrict__ mod_b,
                                                   float* __restrict__ mod) {
    __shared__ __align__(16) char sm[5248];
    const int bid = blockIdx.x;
    if (bid < 4096) {
        const float* src; unsigned short* dst; int C, c0, r0;
        if (bid < 3072) { src = w_qkv; dst = wqkvT; C = 3072; c0 = (bid % 96) * 32; r0 = (bid / 96) * 32; }
        else { int i2 = bid - 3072; src = w_out; dst = woutT; C = 1024; c0 = (i2 & 31) * 32; r0 = (i2 >> 5) * 32; }
        unsigned short (*t)[33] = (unsigned short(*)[33])sm;
        int tx = threadIdx.x & 31, ty = threadIdx.x >> 5;
        #pragma unroll
        for (int i = 0; i < 4; ++i) {
            int r = ty + i * 8;
            t[r][tx] = f2bf(src[(size_t)(r0 + r) * C + c0 + tx]);
        }
        __syncthreads();
        #pragma unroll
        for (int i = 0; i < 4; ++i) {
            int c = ty + i * 8;
            dst[(size_t)(c0 + c) * 1024 + r0 + tx] = t[tx][c];
        }
    } else {
        const int mb = bid - 4096;                // 0..767
        float* st = (float*)sm;                   // 4096 B
        float (*part)[33] = (float(*)[33])(sm + 4096);
        const int b = mb / 96;
        const int jb = mb % 96;
        const int tid = threadIdx.x;
        const int j = jb * 32 + (tid & 31);
        const int sub = tid >> 5;                 // 0..7, covers k = sub*128..+127
        for (int i = tid; i < 1024; i += 256) {
            float t = timep[b * 1024 + i];
            st[i] = t / (1.0f + __expf(-t));      // silu
        }
        __syncthreads();
        float acc = 0.f;
        const int k0 = sub * 128;
        #pragma unroll 4
        for (int m = 0; m < 128; ++m)
            acc = fmaf(st[k0 + m], mod_w[(size_t)(k0 + m) * 3072 + j], acc);
        part[sub][tid & 31] = acc;
        __syncthreads();
        if (tid < 32) {
            float s = mod_b[jb * 32 + tid];
            #pragma unroll
            for (int p = 0; p < 8; ++p) s += part[p][tid];   // fixed order: deterministic
            mod[b * 3072 + jb * 32 + tid] = s;
        }
    }
}

// ---------------- kernel: h = LN(x) * (scale+1) + shift -> bf16; wave-per-row, no LDS/barriers ----------------
__global__ __launch_bounds__(256) void ln_mod_kernel(const float* __restrict__ x,
                                                     const float* __restrict__ mod,
                                                     unsigned short* __restrict__ h) {
    int row = blockIdx.x * 4 + (threadIdx.x >> 6);   // b*1024 + t
    int lane = threadIdx.x & 63;
    int b = row >> 10;
    const float* xr = x + (size_t)row * 1024;
    float4 v[4];
    float s = 0.f, ss = 0.f;
    #pragma unroll
    for (int j = 0; j < 4; ++j) {
        v[j] = *reinterpret_cast<const float4*>(xr + j * 256 + lane * 4);
        s  += v[j].x + v[j].y + v[j].z + v[j].w;
        ss += v[j].x * v[j].x + v[j].y * v[j].y + v[j].z * v[j].z + v[j].w * v[j].w;
    }
    #pragma unroll
    for (int o = 32; o >= 1; o >>= 1) { s += __shfl_xor(s, o); ss += __shfl_xor(ss, o); }
    float mean = s * (1.0f / 1024.0f);
    float rstd = rsqrtf(ss * (1.0f / 1024.0f) - mean * mean + LN_EPS);
    const float* mb = mod + b * 3072;
    #pragma unroll
    for (int j = 0; j < 4; ++j) {
        int d = j * 256 + lane * 4;
        float4 shf = *reinterpret_cast<const float4*>(mb + d);          // shift
        float4 scl = *reinterpret_cast<const float4*>(mb + 1024 + d);   // scale
        ushort4 o4;
        o4.x = f2bf((v[j].x - mean) * rstd * (scl.x + 1.0f) + shf.x);
        o4.y = f2bf((v[j].y - mean) * rstd * (scl.y + 1.0f) + shf.y);
        o4.z = f2bf((v[j].z - mean) * rstd * (scl.z + 1.0f) + shf.z);
        o4.w = f2bf((v[j].w - mean) * rstd * (scl.w + 1.0f) + shf.w);
        *reinterpret_cast<ushort4*>(h + (size_t)row * 1024 + d) = o4;
    }
}

// ---------------- MFMA GEMM main loop (m97 structure): global_load_lds staging ----------------
static __device__ __forceinline__ void gemm_mainloop(const unsigned short* __restrict__ A,
                                                     const unsigned short* __restrict__ Bt,
                                                     int m0, int n0,
                                                     unsigned short* As, unsigned short* Bs,
                                                     f32x4 (&acc)[4][4]) {
    const int tid = threadIdx.x;
    const int wid = tid >> 6, lane = tid & 63;
    const int wr = wid >> 1, wc = wid & 1;
    const int lr = lane & 15, lks = lane >> 4;
    const int gofs = (lane >> 3) * 1024 + (((lane & 7) ^ (lane >> 3)) * 8);
    const unsigned short* Ag = A  + (size_t)(m0 + wid * 32) * 1024 + gofs;
    const unsigned short* Bg = Bt + (size_t)(n0 + wid * 32) * 1024 + gofs;
    unsigned short* AsW = As + wid * 32 * 64;
    unsigned short* BsW = Bs + wid * 32 * 64;
    for (int k0 = 0; k0 < 1024; k0 += 64) {
        __syncthreads();
        #pragma unroll
        for (int j = 0; j < 4; ++j) {
            gl_lds16(Ag + k0 + j * 8192, AsW + j * 512);
            gl_lds16(Bg + k0 + j * 8192, BsW + j * 512);
        }
        __syncthreads();
        #pragma unroll
        for (int ks = 0; ks < 2; ++ks) {
            bf16x8 af[4], bfr[4];
            #pragma unroll
            for (int mi = 0; mi < 4; ++mi) {
                int row = wr * 64 + mi * 16 + lr;
                int ss = (ks * 4 + lks) ^ (row & 7);
                af[mi] = *reinterpret_cast<const bf16x8*>(As + row * 64 + ss * 8);
            }
            #pragma unroll
            for (int ni = 0; ni < 4; ++ni) {
                int row = wc * 64 + ni * 16 + lr;
                int ss = (ks * 4 + lks) ^ (row & 7);
                bfr[ni] = *reinterpret_cast<const bf16x8*>(Bs + row * 64 + ss * 8);
            }
            #pragma unroll
            for (int mi = 0; mi < 4; ++mi)
                #pragma unroll
                for (int ni = 0; ni < 4; ++ni)
                    acc[mi][ni] = __builtin_amdgcn_mfma_f32_16x16x32_bf16(af[mi], bfr[ni], acc[mi][ni], 0, 0, 0);
        }
    }
}

// ---------------- kernel: qkv GEMM (MFMA); q/k scattered (B,H,T,64); v stored TRANSPOSED (B,H,64,T) ----------------
__global__ __launch_bounds__(256) void gemm_qkv_mfma(const unsigned short* __restrict__ A,
                                                     const unsigned short* __restrict__ Bt,
                                                     unsigned short* __restrict__ qb,
                                                     unsigned short* __restrict__ kb,
                                                     unsigned short* __restrict__ vb) {
    __shared__ __align__(16) unsigned short smem[16640];   // As|Bs (16384), bounce uses stride 130
    unsigned short* As = smem;
    unsigned short* Bs = smem + 8192;
    const int bid = blockIdx.y * 24 + blockIdx.x;
    const int xcd = bid & 7, idx = bid >> 3;
    const int m0 = (xcd * 8 + (idx & 7)) * 128;
    const int n0 = (idx >> 3) * 128;
    const int tid = threadIdx.x;
    const int wid = tid >> 6, lane = tid & 63;
    const int wr = wid >> 1, wc = wid & 1;
    const int lr = lane & 15, g = lane >> 4;
    const int which = n0 >> 10;                     // block-uniform: 0=q 1=k 2=v
    f32x4 acc[4][4] = {};
    gemm_mainloop(A, Bt, m0, n0, As, Bs, acc);
    __syncthreads();
    // ---- bounce C tile to LDS (stride 130); v blocks bounce TRANSPOSED ----
    #pragma unroll
    for (int mi = 0; mi < 4; ++mi)
    #pragma unroll
    for (int ni = 0; ni < 4; ++ni)
    #pragma unroll
    for (int r = 0; r < 4; ++r) {
        int row = wr * 64 + mi * 16 + g * 4 + r;
        int col = wc * 64 + ni * 16 + lr;
        if (which == 2) smem[col * 130 + row] = f2bf(acc[mi][ni][r]);
        else            smem[row * 130 + col] = f2bf(acc[mi][ni][r]);
    }
    __syncthreads();
    const int bb = m0 >> 10, tbase = m0 & 1023;
    if (which == 2) {
        // transposed store: 16B along t
        #pragma unroll
        for (int p = 0; p < 8; ++p) {
            int seg = (tid >> 3) + p * 32;          // 0..255
            int erow = seg >> 1, half = seg & 1, sub = tid & 7;
            int4 v = *reinterpret_cast<const int4*>(smem + erow * 130 + half * 64 + sub * 8);
            int eg = (n0 & 1023) + erow;
            int hd = eg >> 6, ei = eg & 63;
            *reinterpret_cast<int4*>(vb + (((size_t)(bb * 16 + hd) * 64 + ei) << 10)
                                        + tbase + half * 64 + sub * 8) = v;
        }
    } else {
        unsigned short* dst = which == 0 ? qb : kb;
        #pragma unroll
        for (int p = 0; p < 8; ++p) {
            int seg = (tid >> 3) + p * 32;
            int row = seg >> 1, half = seg & 1, sub = tid & 7;
            int4 v = *reinterpret_cast<const int4*>(smem + row * 130 + half * 64 + sub * 8);
            int colb = n0 + half * 64;
            int hd = (colb & 1023) >> 6;
            int t = tbase + row;
            *reinterpret_cast<int4*>(dst + (((size_t)(bb * 16 + hd) * 1024 + t) << 6) + sub * 8) = v;
        }
    }
}

// ---------------- kernel: out GEMM (MFMA), 2-pass f32 LDS-bounce, fused gate ----------------
__global__ __launch_bounds__(256) void gemm_out_mfma(const unsigned short* __restrict__ A,
                                                     const unsigned short* __restrict__ Bt,
                                                     const float* __restrict__ mod,
                                                     float* __restrict__ out) {
    __shared__ __align__(16) unsigned short smem[16640];
    unsigned short* As = smem;
    unsigned short* Bs = smem + 8192;
    float* fsm = reinterpret_cast<float*>(smem);           // [64][128] f32 = 32 KB
    const int bid = blockIdx.y * 8 + blockIdx.x;
    const int xcd = bid & 7, idx = bid >> 3;
    const int m0 = (xcd * 8 + (idx & 7)) * 128;
    const int n0 = (idx >> 3) * 128;
    const int tid = threadIdx.x;
    const int wid = tid >> 6, lane = tid & 63;
    const int wr = wid >> 1, wc = wid & 1;
    const int lr = lane & 15, g = lane >> 4;
    f32x4 acc[4][4] = {};
    gemm_mainloop(A, Bt, m0, n0, As, Bs, acc);
    #pragma unroll
    for (int hp = 0; hp < 2; ++hp) {
        __syncthreads();
        if (wr == hp) {
            #pragma unroll
            for (int mi = 0; mi < 4; ++mi)
            #pragma unroll
            for (int ni = 0; ni < 4; ++ni)
            #pragma unroll
            for (int r = 0; r < 4; ++r)
                fsm[(mi * 16 + g * 4 + r) * 128 + wc * 64 + ni * 16 + lr] = acc[mi][ni][r];
        }
        __syncthreads();
        #pragma unroll
        for (int p = 0; p < 8; ++p) {
            int unit = tid + p * 256;
            int lrow = unit >> 5, sub = unit & 31;
            float4 v = *reinterpret_cast<const float4*>(fsm + lrow * 128 + sub * 4);
            int row = m0 + hp * 64 + lrow;
            int col = n0 + sub * 4;
            int bb = row >> 10;
            float4 gv = *reinterpret_cast<const float4*>(mod + bb * 3072 + 2048 + col);
            float4 o4;
            o4.x = v.x * gv.x; o4.y = v.y * gv.y; o4.z = v.z * gv.z; o4.w = v.w * gv.w;
            *reinterpret_cast<float4*>(out + (size_t)row * 1024 + col) = o4;
        }
    }
}

// ---------------- kernel: per-row (e=64) LN + RoPE, 4 rows/wave vectorized ----------------
__global__ __launch_bounds__(256) void lnrope_kernel(unsigned short* __restrict__ qb,
                                                     unsigned short* __restrict__ kb,
                                                     const float* __restrict__ qw,
                                                     const float* __restrict__ kw,
                                                     const float* __restrict__ pos) {
    int gw = blockIdx.x * 4 + (threadIdx.x >> 6);   // wave id 0..65535
    int lane = threadIdx.x & 63;
    int half = gw >> 15;                            // 0 = q, 1 = k
    int rw = (gw * 4 + (lane >> 4)) & 131071;       // row within buffer
    unsigned short* buf = half ? kb : qb;
    const float* w = half ? kw : qw;
    int t = rw & 1023;
    int c4 = (lane & 15) * 4;                       // element base 0..60
    size_t idx = (size_t)rw * 64 + c4;
    ushort4 u = *reinterpret_cast<const ushort4*>(buf + idx);
    float f0 = bf2f(u.x), f1 = bf2f(u.y), f2 = bf2f(u.z), f3 = bf2f(u.w);
    float s1 = f0 + f1 + f2 + f3;
    float s2 = f0 * f0 + f1 * f1 + f2 * f2 + f3 * f3;
    #pragma unroll
    for (int o = 1; o <= 8; o <<= 1) { s1 += __shfl_xor(s1, o); s2 += __shfl_xor(s2, o); }
    float mean = s1 * (1.0f / 64.0f);
    float rstd = rsqrtf(s2 * (1.0f / 64.0f) - mean * mean + LN_EPS);
    float4 wv = *reinterpret_cast<const float4*>(w + c4);
    float y0 = (f0 - mean) * rstd * wv.x;
    float y1 = (f1 - mean) * rstd * wv.y;
    float y2 = (f2 - mean) * rstd * wv.z;
    float y3 = (f3 - mean) * rstd * wv.w;
    if (c4 < 32) {   // rotated half; pairs (y0,y1),(y2,y3) in-lane
        float4 p = *reinterpret_cast<const float4*>(pos + t * 32 + c4);
        float a;
        a = y0; y0 = a * p.x - y1 * p.y; y1 = y1 * p.x + a * p.y;
        a = y2; y2 = a * p.z - y3 * p.w; y3 = y3 * p.z + a * p.w;
    }
    const float SC = half ? 1.0f : QSCALE;          // q: fold 1/8 and log2e (softmax uses exp2)
    ushort4 o;
    o.x = f2bf(y0 * SC); o.y = f2bf(y1 * SC); o.z = f2bf(y2 * SC); o.w = f2bf(y3 * SC);
    *reinterpret_cast<ushort4*>(buf + idx) = o;
}

// ---------------- kernel: MFMA flash attention (R19 form) ----------------
// KVBLK=64, no-max exp2 softmax, double-buffered K/V via global_load_lds,
// 40 KB LDS -> 4 blocks/CU; precomputed swizzled offsets; lane-partial l (VALU).
__global__ __launch_bounds__(256) void attn_mfma_kernel(const unsigned short* __restrict__ qb,
                                                        const unsigned short* __restrict__ kb,
                                                        const unsigned short* __restrict__ vt,
                                                        unsigned short* __restrict__ ob) {
    __shared__ __align__(16) unsigned char smem[40960];
    unsigned short* KsB = (unsigned short*)smem;            // 2 x [64 kv][64 d]   (2 x 8 KB)
    unsigned short* VsB = (unsigned short*)(smem + 16384);  // 2 x [64 d][64 kv]   (2 x 8 KB)
    unsigned short* paQ = (unsigned short*)(smem + 32768);  // Q stage (8 KB), then pa[4][16][64] (8 KB)

    const int bid = blockIdx.x;
    const int swz = (bid & 7) * 256 + (bid >> 3);           // XCD-chunked
    const int bh = swz >> 4;
    const int q0 = (swz & 15) * 64;
    const int b = bh >> 4, hd = bh & 15;
    const size_t base = (size_t)bh << 16;                   // bh * 1024 * 64
    const int tid = threadIdx.x, wid = tid >> 6, lane = tid & 63;
    const int lr = lane & 15, g = lane >> 4;

    // ---- precomputed swizzled LDS offsets (loop-invariant; live in VGPRs) ----
    int kRd[2][4], pRd[2], pwOff[4][4];
    #pragma unroll
    for (int ks = 0; ks < 2; ++ks) {
        pRd[ks] = lr * 64 + (((ks * 4 + g) ^ (lr & 7)) * 8);
        #pragma unroll
        for (int nt = 0; nt < 4; ++nt)
            kRd[ks][nt] = (nt * 16 + lr) * 64 + (((ks * 4 + g) ^ (lr & 7)) * 8);
    }
    #pragma unroll
    for (int nt = 0; nt < 4; ++nt)
    #pragma unroll
    for (int r = 0; r < 4; ++r) {
        int q = g * 4 + r;
        pwOff[nt][r] = q * 64 + (((nt * 2 + (lr >> 3)) ^ (q & 7)) * 8) + (lr & 7);
    }

    // per-lane pre-swizzled global source pointers for K/V staging
    const unsigned short* kSrc[2];
    const unsigned short* vSrc[2];
    #pragma unroll
    for (int p = 0; p < 2; ++p) {
        int idx = p * 256 + tid;
        int r = idx >> 3, sg = idx & 7;
        kSrc[p] = kb + base + (size_t)r * 64 + ((sg ^ (r & 7)) * 8);
        vSrc[p] = vt + base + (size_t)r * 1024 + ((sg ^ (r & 7)) * 8);
    }

    // ---- prologue: stage chunk 0 (buf 0) + stage Q ----
    #pragma unroll
    for (int p = 0; p < 2; ++p) {
        gl_lds16(kSrc[p], KsB + p * 2048 + wid * 512);
        gl_lds16(vSrc[p], VsB + p * 2048 + wid * 512);
    }
    #pragma unroll
    for (int p = 0; p < 2; ++p) {
        int r = (tid >> 3) + p * 32;
        int sseg = tid & 7;
        int4 qv = *reinterpret_cast<const int4*>(qb + base + (size_t)(q0 + r) * 64 + sseg * 8);
        *reinterpret_cast<int4*>(paQ + r * 64 + ((sseg ^ (r & 7)) * 8)) = qv;
    }
    __syncthreads();
    bf16x8 af[2];
    #pragma unroll
    for (int ks = 0; ks < 2; ++ks) {
        int row = wid * 16 + lr;
        af[ks] = *reinterpret_cast<const bf16x8*>(paQ + row * 64 + (((ks * 4 + g) ^ (row & 7)) * 8));
    }
    __syncthreads();   // af extraction done before any pa write

    f32x4 acc[4] = {};
    float l_par[4] = {0.f, 0.f, 0.f, 0.f};     // lane-partial denominators
    unsigned short* pa_w = paQ + wid * 1024;   // wave-private P [16 q][64 kv] swizzled
    const f32x4 zero4 = {0.f, 0.f, 0.f, 0.f};

    for (int cc = 0; cc < 16; ++cc) {
        const int cur = cc & 1;
        // ---- issue async prefetch of chunk cc+1 into the other buffer ----
        if (cc < 15) {
            const int kv1 = (cc + 1) * 64;
            unsigned short* Kd = KsB + (cur ^ 1) * 4096;
            unsigned short* Vd = VsB + (cur ^ 1) * 4096;
            #pragma unroll
            for (int p = 0; p < 2; ++p) {
                gl_lds16(kSrc[p] + (size_t)kv1 * 64, Kd + p * 2048 + wid * 512);
                gl_lds16(vSrc[p] + kv1,              Vd + p * 2048 + wid * 512);
            }
        }
        const unsigned short* Kc = KsB + cur * 4096;
        const unsigned short* Vc = VsB + cur * 4096;
        // ---- QK^T: S[16 q][64 kv] per wave (8 MFMAs); first ks uses C=0 ----
        f32x4 s[4];
        __builtin_amdgcn_s_setprio(1);
        #pragma unroll
        for (int nt = 0; nt < 4; ++nt) {
            bf16x8 kf = *reinterpret_cast<const bf16x8*>(Kc + kRd[0][nt]);
            s[nt] = __builtin_amdgcn_mfma_f32_16x16x32_bf16(af[0], kf, zero4, 0, 0, 0);
        }
        #pragma unroll
        for (int nt = 0; nt < 4; ++nt) {
            bf16x8 kf = *reinterpret_cast<const bf16x8*>(Kc + kRd[1][nt]);
            s[nt] = __builtin_amdgcn_mfma_f32_16x16x32_bf16(af[1], kf, s[nt], 0, 0, 0);
        }
        __builtin_amdgcn_s_setprio(0);
        // ---- no-max softmax: P = exp2(s), lane-partial l ----
        #pragma unroll
        for (int r = 0; r < 4; ++r)
        #pragma unroll
        for (int nt = 0; nt < 4; ++nt) {
            float e = exp2f(s[nt][r]);
            s[nt][r] = e;
            l_par[r] += e;
        }
        // ---- write P (bf16) to wave-private LDS in A-fragment layout ----
        #pragma unroll
        for (int nt = 0; nt < 4; ++nt)
        #pragma unroll
        for (int r = 0; r < 4; ++r) {
            unsigned int pk;
            asm("v_cvt_pk_bf16_f32 %0, %1, %2" : "=v"(pk) : "v"(s[nt][r]), "v"(0.f));
            pa_w[pwOff[nt][r]] = (unsigned short)pk;
        }
        // ---- PV: O += P @ V (8 MFMAs) ----
        __builtin_amdgcn_s_setprio(1);
        #pragma unroll
        for (int ks = 0; ks < 2; ++ks) {
            bf16x8 paf = *reinterpret_cast<const bf16x8*>(pa_w + pRd[ks]);
            #pragma unroll
            for (int nt = 0; nt < 4; ++nt) {
                bf16x8 vf = *reinterpret_cast<const bf16x8*>(Vc + kRd[ks][nt]);
                acc[nt] = __builtin_amdgcn_mfma_f32_16x16x32_bf16(paf, vf, acc[nt], 0, 0, 0);
            }
        }
        __builtin_amdgcn_s_setprio(0);
        // one barrier: all reads of buf[cur] done (next iter overwrites it) AND
        // drains vmcnt so the cc+1 prefetch is visible for the next iteration.
        __syncthreads();
    }
    // ---- final: reduce lane-partial l, O/l, write (B, T, H*64) ----
    float inv[4];
    #pragma unroll
    for (int r = 0; r < 4; ++r) {
        float l = l_par[r];
        #pragma unroll
        for (int o = 1; o <= 8; o <<= 1) l += __shfl_xor(l, o);
        inv[r] = 1.0f / l;
    }
    #pragma unroll
    for (int nt = 0; nt < 4; ++nt)
    #pragma unroll
    for (int r = 0; r < 4; ++r) {
        int q = q0 + wid * 16 + g * 4 + r;
        int d = hd * 64 + nt * 16 + lr;
        ob[(size_t)(b * 1024 + q) * 1024 + d] = f2bf(acc[nt][r] * inv[r]);
    }
}

extern "C" void kernel_launch(void* const* d_in, const int* in_sizes, int n_in,
                              void* d_out, int out_size, void* d_ws, size_t ws_size,
                              hipStream_t stream) {
    const float* x      = (const float*)d_in[0];
    const float* timep  = (const float*)d_in[1];
    const float* pos    = (const float*)d_in[2];
    const float* mod_w  = (const float*)d_in[3];
    const float* mod_b  = (const float*)d_in[4];
    const float* w_qkv  = (const float*)d_in[5];
    const float* w_out  = (const float*)d_in[6];
    const float* qw     = (const float*)d_in[7];
    const float* kw     = (const float*)d_in[8];
    float* outp = (float*)d_out;                   // f32 (8,1024,1024)

    char* ws = (char*)d_ws;
    float*          modbuf = (float*)ws;                          // 98304 B
    unsigned short* wqkvT  = (unsigned short*)(ws + 98304);       // bf16 [3072][1024]
    unsigned short* woutT  = (unsigned short*)(ws + 6389760);     // bf16 [1024][1024]
    unsigned short* hbuf   = (unsigned short*)(ws + 8486912);     // 16 MB (h, then o)
    unsigned short* qbuf   = hbuf + 8388608;
    unsigned short* kbuf   = qbuf + 8388608;
    unsigned short* vbuf   = kbuf + 8388608;       // v in (B,H,64,T) layout
    unsigned short* obuf   = hbuf;

    prep_kernel<<<4864, 256, 0, stream>>>(w_qkv, wqkvT, w_out, woutT, timep, mod_w, mod_b, modbuf);
    ln_mod_kernel<<<2048, 256, 0, stream>>>(x, modbuf, hbuf);
    gemm_qkv_mfma<<<dim3(24, 64), 256, 0, stream>>>(hbuf, wqkvT, qbuf, kbuf, vbuf);
    lnrope_kernel<<<16384, 256, 0, stream>>>(qbuf, kbuf, qw, kw, pos);
    attn_mfma_kernel<<<2048, 256, 0, stream>>>(qbuf, kbuf, vbuf, obuf);
    gemm_out_mfma<<<dim3(8, 64), 256, 0, stream>>>(obuf, woutT, modbuf, outp);
}

// Round 23
// 192.057 us; speedup vs baseline: 1.1419x; 1.0378x over previous
//
#include <hip/hip_runtime.h>

typedef short bf16x8 __attribute__((ext_vector_type(8)));
typedef float f32x4 __attribute__((ext_vector_type(4)));

#define LN_EPS 1e-6f
#define QSCALE 0.1803368801111143f   // 0.125 * log2(e)

static __device__ __forceinline__ float bf2f(unsigned short u) {
    union { unsigned int i; float f; } v; v.i = ((unsigned int)u) << 16; return v.f;
}
static __device__ __forceinline__ unsigned short f2bf(float f) {
    union { float ff; unsigned int i; } v; v.ff = f;
    return (unsigned short)((v.i + 0x7FFFu + ((v.i >> 16) & 1u)) >> 16);  // RNE
}
// async global->LDS, 16B per lane; LDS dest is wave-uniform base + lane*16
static __device__ __forceinline__ void gl_lds16(const unsigned short* g, unsigned short* l) {
    __builtin_amdgcn_global_load_lds((__attribute__((address_space(1))) void*)g,
                                     (__attribute__((address_space(3))) void*)l,
                                     16, 0, 0);
}

// ---------------- kernel: fused prep = {transpose w_qkv, transpose w_out, mod} ----------------
// blocks 0..3071: transpose w_qkv; 3072..4095: transpose w_out; 4096..4863: mod (K-split x8).
__global__ __launch_bounds__(256) void prep_kernel(const float* __restrict__ w_qkv,
                                                   unsigned short* __restrict__ wqkvT,
                                                   const float* __restrict__ w_out,
                                                   unsigned short* __restrict__ woutT,
                                                   const float* __restrict__ timep,
                                                   const float* __restrict__ mod_w,
                                                   const float* __restrict__ mod_b,
                                                   float* __restrict__ mod) {
    __shared__ __align__(16) char sm[5248];
    const int bid = blockIdx.x;
    if (bid < 4096) {
        const float* src; unsigned short* dst; int C, c0, r0;
        if (bid < 3072) { src = w_qkv; dst = wqkvT; C = 3072; c0 = (bid % 96) * 32; r0 = (bid / 96) * 32; }
        else { int i2 = bid - 3072; src = w_out; dst = woutT; C = 1024; c0 = (i2 & 31) * 32; r0 = (i2 >> 5) * 32; }
        unsigned short (*t)[33] = (unsigned short(*)[33])sm;
        int tx = threadIdx.x & 31, ty = threadIdx.x >> 5;
        #pragma unroll
        for (int i = 0; i < 4; ++i) {
            int r = ty + i * 8;
            t[r][tx] = f2bf(src[(size_t)(r0 + r) * C + c0 + tx]);
        }
        __syncthreads();
        #pragma unroll
        for (int i = 0; i < 4; ++i) {
            int c = ty + i * 8;
            dst[(size_t)(c0 + c) * 1024 + r0 + tx] = t[tx][c];
        }
    } else {
        const int mb = bid - 4096;                // 0..767
        float* st = (float*)sm;                   // 4096 B
        float (*part)[33] = (float(*)[33])(sm + 4096);
        const int b = mb / 96;
        const int jb = mb % 96;
        const int tid = threadIdx.x;
        const int j = jb * 32 + (tid & 31);
        const int sub = tid >> 5;                 // 0..7, covers k = sub*128..+127
        for (int i = tid; i < 1024; i += 256) {
            float t = timep[b * 1024 + i];
            st[i] = t / (1.0f + __expf(-t));      // silu
        }
        __syncthreads();
        float acc = 0.f;
        const int k0 = sub * 128;
        #pragma unroll 4
        for (int m = 0; m < 128; ++m)
            acc = fmaf(st[k0 + m], mod_w[(size_t)(k0 + m) * 3072 + j], acc);
        part[sub][tid & 31] = acc;
        __syncthreads();
        if (tid < 32) {
            float s = mod_b[jb * 32 + tid];
            #pragma unroll
            for (int p = 0; p < 8; ++p) s += part[p][tid];   // fixed order: deterministic
            mod[b * 3072 + jb * 32 + tid] = s;
        }
    }
}

// ---------------- kernel: h = LN(x) * (scale+1) + shift -> bf16; wave-per-row, no LDS/barriers ----------------
__global__ __launch_bounds__(256) void ln_mod_kernel(const float* __restrict__ x,
                                                     const float* __restrict__ mod,
                                                     unsigned short* __restrict__ h) {
    int row = blockIdx.x * 4 + (threadIdx.x >> 6);   // b*1024 + t
    int lane = threadIdx.x & 63;
    int b = row >> 10;
    const float* xr = x + (size_t)row * 1024;
    float4 v[4];
    float s = 0.f, ss = 0.f;
    #pragma unroll
    for (int j = 0; j < 4; ++j) {
        v[j] = *reinterpret_cast<const float4*>(xr + j * 256 + lane * 4);
        s  += v[j].x + v[j].y + v[j].z + v[j].w;
        ss += v[j].x * v[j].x + v[j].y * v[j].y + v[j].z * v[j].z + v[j].w * v[j].w;
    }
    #pragma unroll
    for (int o = 32; o >= 1; o >>= 1) { s += __shfl_xor(s, o); ss += __shfl_xor(ss, o); }
    float mean = s * (1.0f / 1024.0f);
    float rstd = rsqrtf(ss * (1.0f / 1024.0f) - mean * mean + LN_EPS);
    const float* mb = mod + b * 3072;
    #pragma unroll
    for (int j = 0; j < 4; ++j) {
        int d = j * 256 + lane * 4;
        float4 shf = *reinterpret_cast<const float4*>(mb + d);          // shift
        float4 scl = *reinterpret_cast<const float4*>(mb + 1024 + d);   // scale
        ushort4 o4;
        o4.x = f2bf((v[j].x - mean) * rstd * (scl.x + 1.0f) + shf.x);
        o4.y = f2bf((v[j].y - mean) * rstd * (scl.y + 1.0f) + shf.y);
        o4.z = f2bf((v[j].z - mean) * rstd * (scl.z + 1.0f) + shf.z);
        o4.w = f2bf((v[j].w - mean) * rstd * (scl.w + 1.0f) + shf.w);
        *reinterpret_cast<ushort4*>(h + (size_t)row * 1024 + d) = o4;
    }
}

// ---------------- MFMA GEMM main loop (m97 structure): global_load_lds staging ----------------
static __device__ __forceinline__ void gemm_mainloop(const unsigned short* __restrict__ A,
                                                     const unsigned short* __restrict__ Bt,
                                                     int m0, int n0,
                                                     unsigned short* As, unsigned short* Bs,
                                                     f32x4 (&acc)[4][4]) {
    const int tid = threadIdx.x;
    const int wid = tid >> 6, lane = tid & 63;
    const int wr = wid >> 1, wc = wid & 1;
    const int lr = lane & 15, lks = lane >> 4;
    const int gofs = (lane >> 3) * 1024 + (((lane & 7) ^ (lane >> 3)) * 8);
    const unsigned short* Ag = A  + (size_t)(m0 + wid * 32) * 1024 + gofs;
    const unsigned short* Bg = Bt + (size_t)(n0 + wid * 32) * 1024 + gofs;
    unsigned short* AsW = As + wid * 32 * 64;
    unsigned short* BsW = Bs + wid * 32 * 64;
    for (int k0 = 0; k0 < 1024; k0 += 64) {
        __syncthreads();
        #pragma unroll
        for (int j = 0; j < 4; ++j) {
            gl_lds16(Ag + k0 + j * 8192, AsW + j * 512);
            gl_lds16(Bg + k0 + j * 8192, BsW + j * 512);
        }
        __syncthreads();
        #pragma unroll
        for (int ks = 0; ks < 2; ++ks) {
            bf16x8 af[4], bfr[4];
            #pragma unroll
            for (int mi = 0; mi < 4; ++mi) {
                int row = wr * 64 + mi * 16 + lr;
                int ss = (ks * 4 + lks) ^ (row & 7);
                af[mi] = *reinterpret_cast<const bf16x8*>(As + row * 64 + ss * 8);
            }
            #pragma unroll
            for (int ni = 0; ni < 4; ++ni) {
                int row = wc * 64 + ni * 16 + lr;
                int ss = (ks * 4 + lks) ^ (row & 7);
                bfr[ni] = *reinterpret_cast<const bf16x8*>(Bs + row * 64 + ss * 8);
            }
            #pragma unroll
            for (int mi = 0; mi < 4; ++mi)
                #pragma unroll
                for (int ni = 0; ni < 4; ++ni)
                    acc[mi][ni] = __builtin_amdgcn_mfma_f32_16x16x32_bf16(af[mi], bfr[ni], acc[mi][ni], 0, 0, 0);
        }
    }
}

// ---------------- kernel: qkv GEMM (MFMA); q/k scattered (B,H,T,64); v stored TRANSPOSED (B,H,64,T) ----------------
__global__ __launch_bounds__(256) void gemm_qkv_mfma(const unsigned short* __restrict__ A,
                                                     const unsigned short* __restrict__ Bt,
                                                     unsigned short* __restrict__ qb,
                                                     unsigned short* __restrict__ kb,
                                                     unsigned short* __restrict__ vb) {
    __shared__ __align__(16) unsigned short smem[16640];   // As|Bs (16384), bounce uses stride 130
    unsigned short* As = smem;
    unsigned short* Bs = smem + 8192;
    const int bid = blockIdx.y * 24 + blockIdx.x;
    const int xcd = bid & 7, idx = bid >> 3;
    const int m0 = (xcd * 8 + (idx & 7)) * 128;
    const int n0 = (idx >> 3) * 128;
    const int tid = threadIdx.x;
    const int wid = tid >> 6, lane = tid & 63;
    const int wr = wid >> 1, wc = wid & 1;
    const int lr = lane & 15, g = lane >> 4;
    const int which = n0 >> 10;                     // block-uniform: 0=q 1=k 2=v
    f32x4 acc[4][4] = {};
    gemm_mainloop(A, Bt, m0, n0, As, Bs, acc);
    __syncthreads();
    // ---- bounce C tile to LDS (stride 130); v blocks bounce TRANSPOSED ----
    #pragma unroll
    for (int mi = 0; mi < 4; ++mi)
    #pragma unroll
    for (int ni = 0; ni < 4; ++ni)
    #pragma unroll
    for (int r = 0; r < 4; ++r) {
        int row = wr * 64 + mi * 16 + g * 4 + r;
        int col = wc * 64 + ni * 16 + lr;
        if (which == 2) smem[col * 130 + row] = f2bf(acc[mi][ni][r]);
        else            smem[row * 130 + col] = f2bf(acc[mi][ni][r]);
    }
    __syncthreads();
    const int bb = m0 >> 10, tbase = m0 & 1023;
    if (which == 2) {
        // transposed store: 16B along t
        #pragma unroll
        for (int p = 0; p < 8; ++p) {
            int seg = (tid >> 3) + p * 32;          // 0..255
            int erow = seg >> 1, half = seg & 1, sub = tid & 7;
            int4 v = *reinterpret_cast<const int4*>(smem + erow * 130 + half * 64 + sub * 8);
            int eg = (n0 & 1023) + erow;
            int hd = eg >> 6, ei = eg & 63;
            *reinterpret_cast<int4*>(vb + (((size_t)(bb * 16 + hd) * 64 + ei) << 10)
                                        + tbase + half * 64 + sub * 8) = v;
        }
    } else {
        unsigned short* dst = which == 0 ? qb : kb;
        #pragma unroll
        for (int p = 0; p < 8; ++p) {
            int seg = (tid >> 3) + p * 32;
            int row = seg >> 1, half = seg & 1, sub = tid & 7;
            int4 v = *reinterpret_cast<const int4*>(smem + row * 130 + half * 64 + sub * 8);
            int colb = n0 + half * 64;
            int hd = (colb & 1023) >> 6;
            int t = tbase + row;
            *reinterpret_cast<int4*>(dst + (((size_t)(bb * 16 + hd) * 1024 + t) << 6) + sub * 8) = v;
        }
    }
}

// ---------------- kernel: out GEMM (MFMA), 2-pass f32 LDS-bounce, fused gate ----------------
__global__ __launch_bounds__(256) void gemm_out_mfma(const unsigned short* __restrict__ A,
                                                     const unsigned short* __restrict__ Bt,
                                                     const float* __restrict__ mod,
                                                     float* __restrict__ out) {
    __shared__ __align__(16) unsigned short smem[16640];
    unsigned short* As = smem;
    unsigned short* Bs = smem + 8192;
    float* fsm = reinterpret_cast<float*>(smem);           // [64][128] f32 = 32 KB
    const int bid = blockIdx.y * 8 + blockIdx.x;
    const int xcd = bid & 7, idx = bid >> 3;
    const int m0 = (xcd * 8 + (idx & 7)) * 128;
    const int n0 = (idx >> 3) * 128;
    const int tid = threadIdx.x;
    const int wid = tid >> 6, lane = tid & 63;
    const int wr = wid >> 1, wc = wid & 1;
    const int lr = lane & 15, g = lane >> 4;
    f32x4 acc[4][4] = {};
    gemm_mainloop(A, Bt, m0, n0, As, Bs, acc);
    #pragma unroll
    for (int hp = 0; hp < 2; ++hp) {
        __syncthreads();
        if (wr == hp) {
            #pragma unroll
            for (int mi = 0; mi < 4; ++mi)
            #pragma unroll
            for (int ni = 0; ni < 4; ++ni)
            #pragma unroll
            for (int r = 0; r < 4; ++r)
                fsm[(mi * 16 + g * 4 + r) * 128 + wc * 64 + ni * 16 + lr] = acc[mi][ni][r];
        }
        __syncthreads();
        #pragma unroll
        for (int p = 0; p < 8; ++p) {
            int unit = tid + p * 256;
            int lrow = unit >> 5, sub = unit & 31;
            float4 v = *reinterpret_cast<const float4*>(fsm + lrow * 128 + sub * 4);
            int row = m0 + hp * 64 + lrow;
            int col = n0 + sub * 4;
            int bb = row >> 10;
            float4 gv = *reinterpret_cast<const float4*>(mod + bb * 3072 + 2048 + col);
            float4 o4;
            o4.x = v.x * gv.x; o4.y = v.y * gv.y; o4.z = v.z * gv.z; o4.w = v.w * gv.w;
            *reinterpret_cast<float4*>(out + (size_t)row * 1024 + col) = o4;
        }
    }
}

// ---------------- kernel: per-row (e=64) LN + RoPE, 4 rows/wave vectorized ----------------
__global__ __launch_bounds__(256) void lnrope_kernel(unsigned short* __restrict__ qb,
                                                     unsigned short* __restrict__ kb,
                                                     const float* __restrict__ qw,
                                                     const float* __restrict__ kw,
                                                     const float* __restrict__ pos) {
    int gw = blockIdx.x * 4 + (threadIdx.x >> 6);   // wave id 0..65535
    int lane = threadIdx.x & 63;
    int half = gw >> 15;                            // 0 = q, 1 = k
    int rw = (gw * 4 + (lane >> 4)) & 131071;       // row within buffer
    unsigned short* buf = half ? kb : qb;
    const float* w = half ? kw : qw;
    int t = rw & 1023;
    int c4 = (lane & 15) * 4;                       // element base 0..60
    size_t idx = (size_t)rw * 64 + c4;
    ushort4 u = *reinterpret_cast<const ushort4*>(buf + idx);
    float f0 = bf2f(u.x), f1 = bf2f(u.y), f2 = bf2f(u.z), f3 = bf2f(u.w);
    float s1 = f0 + f1 + f2 + f3;
    float s2 = f0 * f0 + f1 * f1 + f2 * f2 + f3 * f3;
    #pragma unroll
    for (int o = 1; o <= 8; o <<= 1) { s1 += __shfl_xor(s1, o); s2 += __shfl_xor(s2, o); }
    float mean = s1 * (1.0f / 64.0f);
    float rstd = rsqrtf(s2 * (1.0f / 64.0f) - mean * mean + LN_EPS);
    float4 wv = *reinterpret_cast<const float4*>(w + c4);
    float y0 = (f0 - mean) * rstd * wv.x;
    float y1 = (f1 - mean) * rstd * wv.y;
    float y2 = (f2 - mean) * rstd * wv.z;
    float y3 = (f3 - mean) * rstd * wv.w;
    if (c4 < 32) {   // rotated half; pairs (y0,y1),(y2,y3) in-lane
        float4 p = *reinterpret_cast<const float4*>(pos + t * 32 + c4);
        float a;
        a = y0; y0 = a * p.x - y1 * p.y; y1 = y1 * p.x + a * p.y;
        a = y2; y2 = a * p.z - y3 * p.w; y3 = y3 * p.z + a * p.w;
    }
    const float SC = half ? 1.0f : QSCALE;          // q: fold 1/8 and log2e (softmax uses exp2)
    ushort4 o;
    o.x = f2bf(y0 * SC); o.y = f2bf(y1 * SC); o.z = f2bf(y2 * SC); o.w = f2bf(y3 * SC);
    *reinterpret_cast<ushort4*>(buf + idx) = o;
}

// ---------------- kernel: MFMA flash attention v9 (QBLK=128, 8 waves) ----------------
// KVBLK=64, no-max exp2 softmax, double-buffered K/V via global_load_lds.
// 48 KB LDS -> 3 blocks/CU x 8 waves = 24 waves/CU; K/V fetch amortized over 128 q rows.
// Per-wave inner loop identical to the proven R19 form (wave owns 16 q rows).
__global__ __launch_bounds__(512) void attn_mfma_kernel(const unsigned short* __restrict__ qb,
                                                        const unsigned short* __restrict__ kb,
                                                        const unsigned short* __restrict__ vt,
                                                        unsigned short* __restrict__ ob) {
    __shared__ __align__(16) unsigned char smem[49152];
    unsigned short* KsB = (unsigned short*)smem;            // 2 x [64 kv][64 d]   (2 x 8 KB)
    unsigned short* VsB = (unsigned short*)(smem + 16384);  // 2 x [64 d][64 kv]   (2 x 8 KB)
    unsigned short* paQ = (unsigned short*)(smem + 32768);  // Q stage (16 KB), then pa[8][16][64] (8 KB)

    const int bid = blockIdx.x;                             // 0..1023
    const int swz = (bid & 7) * 128 + (bid >> 3);           // XCD-chunked
    const int bh = swz >> 3;                                // 0..127
    const int q0 = (swz & 7) * 128;                         // 0..896
    const int b = bh >> 4, hd = bh & 15;
    const size_t base = (size_t)bh << 16;                   // bh * 1024 * 64
    const int tid = threadIdx.x, wid = tid >> 6, lane = tid & 63;
    const int lr = lane & 15, g = lane >> 4;

    // ---- precomputed swizzled LDS offsets (loop-invariant; live in VGPRs) ----
    int kRd[2][4], pRd[2], pwOff[4][4];
    #pragma unroll
    for (int ks = 0; ks < 2; ++ks) {
        pRd[ks] = lr * 64 + (((ks * 4 + g) ^ (lr & 7)) * 8);
        #pragma unroll
        for (int nt = 0; nt < 4; ++nt)
            kRd[ks][nt] = (nt * 16 + lr) * 64 + (((ks * 4 + g) ^ (lr & 7)) * 8);
    }
    #pragma unroll
    for (int nt = 0; nt < 4; ++nt)
    #pragma unroll
    for (int r = 0; r < 4; ++r) {
        int q = g * 4 + r;
        pwOff[nt][r] = q * 64 + (((nt * 2 + (lr >> 3)) ^ (q & 7)) * 8) + (lr & 7);
    }

    // per-lane pre-swizzled global source pointers for K/V staging
    // 512 threads x 16B = 8 KB = one full chunk per issue
    const int sr = tid >> 3, ssg = tid & 7;
    const unsigned short* kSrc = kb + base + (size_t)sr * 64 + ((ssg ^ (sr & 7)) * 8);
    const unsigned short* vSrc = vt + base + (size_t)sr * 1024 + ((ssg ^ (sr & 7)) * 8);

    // ---- prologue: stage chunk 0 (buf 0) + stage Q (128 rows, 2 passes) ----
    gl_lds16(kSrc, KsB + wid * 512);
    gl_lds16(vSrc, VsB + wid * 512);
    #pragma unroll
    for (int p = 0; p < 2; ++p) {
        int r = (tid >> 3) + p * 64;
        int4 qv = *reinterpret_cast<const int4*>(qb + base + (size_t)(q0 + r) * 64 + ssg * 8);
        *reinterpret_cast<int4*>(paQ + r * 64 + ((ssg ^ (r & 7)) * 8)) = qv;
    }
    __syncthreads();
    bf16x8 af[2];
    #pragma unroll
    for (int ks = 0; ks < 2; ++ks) {
        int row = wid * 16 + lr;
        af[ks] = *reinterpret_cast<const bf16x8*>(paQ + row * 64 + (((ks * 4 + g) ^ (row & 7)) * 8));
    }
    __syncthreads();   // af extraction done before any pa write

    f32x4 acc[4] = {};
    float l_par[4] = {0.f, 0.f, 0.f, 0.f};     // lane-partial denominators
    unsigned short* pa_w = paQ + wid * 1024;   // wave-private P [16 q][64 kv] swizzled
    const f32x4 zero4 = {0.f, 0.f, 0.f, 0.f};

    for (int cc = 0; cc < 16; ++cc) {
        const int cur = cc & 1;
        // ---- issue async prefetch of chunk cc+1 into the other buffer ----
        if (cc < 15) {
            const int kv1 = (cc + 1) * 64;
            gl_lds16(kSrc + (size_t)kv1 * 64, KsB + (cur ^ 1) * 4096 + wid * 512);
            gl_lds16(vSrc + kv1,              VsB + (cur ^ 1) * 4096 + wid * 512);
        }
        const unsigned short* Kc = KsB + cur * 4096;
        const unsigned short* Vc = VsB + cur * 4096;
        // ---- QK^T: S[16 q][64 kv] per wave (8 MFMAs); first ks uses C=0 ----
        f32x4 s[4];
        __builtin_amdgcn_s_setprio(1);
        #pragma unroll
        for (int nt = 0; nt < 4; ++nt) {
            bf16x8 kf = *reinterpret_cast<const bf16x8*>(Kc + kRd[0][nt]);
            s[nt] = __builtin_amdgcn_mfma_f32_16x16x32_bf16(af[0], kf, zero4, 0, 0, 0);
        }
        #pragma unroll
        for (int nt = 0; nt < 4; ++nt) {
            bf16x8 kf = *reinterpret_cast<const bf16x8*>(Kc + kRd[1][nt]);
            s[nt] = __builtin_amdgcn_mfma_f32_16x16x32_bf16(af[1], kf, s[nt], 0, 0, 0);
        }
        __builtin_amdgcn_s_setprio(0);
        // ---- no-max softmax: P = exp2(s), lane-partial l ----
        #pragma unroll
        for (int r = 0; r < 4; ++r)
        #pragma unroll
        for (int nt = 0; nt < 4; ++nt) {
            float e = exp2f(s[nt][r]);
            s[nt][r] = e;
            l_par[r] += e;
        }
        // ---- write P (bf16) to wave-private LDS in A-fragment layout ----
        #pragma unroll
        for (int nt = 0; nt < 4; ++nt)
        #pragma unroll
        for (int r = 0; r < 4; ++r) {
            unsigned int pk;
            asm("v_cvt_pk_bf16_f32 %0, %1, %2" : "=v"(pk) : "v"(s[nt][r]), "v"(0.f));
            pa_w[pwOff[nt][r]] = (unsigned short)pk;
        }
        // ---- PV: O += P @ V (8 MFMAs) ----
        __builtin_amdgcn_s_setprio(1);
        #pragma unroll
        for (int ks = 0; ks < 2; ++ks) {
            bf16x8 paf = *reinterpret_cast<const bf16x8*>(pa_w + pRd[ks]);
            #pragma unroll
            for (int nt = 0; nt < 4; ++nt) {
                bf16x8 vf = *reinterpret_cast<const bf16x8*>(Vc + kRd[ks][nt]);
                acc[nt] = __builtin_amdgcn_mfma_f32_16x16x32_bf16(paf, vf, acc[nt], 0, 0, 0);
            }
        }
        __builtin_amdgcn_s_setprio(0);
        // one barrier: all reads of buf[cur] done (next iter overwrites it) AND
        // drains vmcnt so the cc+1 prefetch is visible for the next iteration.
        __syncthreads();
    }
    // ---- final: reduce lane-partial l, O/l, write (B, T, H*64) ----
    float inv[4];
    #pragma unroll
    for (int r = 0; r < 4; ++r) {
        float l = l_par[r];
        #pragma unroll
        for (int o = 1; o <= 8; o <<= 1) l += __shfl_xor(l, o);
        inv[r] = 1.0f / l;
    }
    #pragma unroll
    for (int nt = 0; nt < 4; ++nt)
    #pragma unroll
    for (int r = 0; r < 4; ++r) {
        int q = q0 + wid * 16 + g * 4 + r;
        int d = hd * 64 + nt * 16 + lr;
        ob[(size_t)(b * 1024 + q) * 1024 + d] = f2bf(acc[nt][r] * inv[r]);
    }
}

extern "C" void kernel_launch(void* const* d_in, const int* in_sizes, int n_in,
                              void* d_out, int out_size, void* d_ws, size_t ws_size,
                              hipStream_t stream) {
    const float* x      = (const float*)d_in[0];
    const float* timep  = (const float*)d_in[1];
    const float* pos    = (const float*)d_in[2];
    const float* mod_w  = (const float*)d_in[3];
    const float* mod_b  = (const float*)d_in[4];
    const float* w_qkv  = (const float*)d_in[5];
    const float* w_out  = (const float*)d_in[6];
    const float* qw     = (const float*)d_in[7];
    const float* kw     = (const float*)d_in[8];
    float* outp = (float*)d_out;                   // f32 (8,1024,1024)

    char* ws = (char*)d_ws;
    float*          modbuf = (float*)ws;                          // 98304 B
    unsigned short* wqkvT  = (unsigned short*)(ws + 98304);       // bf16 [3072][1024]
    unsigned short* woutT  = (unsigned short*)(ws + 6389760);     // bf16 [1024][1024]
    unsigned short* hbuf   = (unsigned short*)(ws + 8486912);     // 16 MB (h, then o)
    unsigned short* qbuf   = hbuf + 8388608;
    unsigned short* kbuf   = qbuf + 8388608;
    unsigned short* vbuf   = kbuf + 8388608;       // v in (B,H,64,T) layout
    unsigned short* obuf   = hbuf;

    prep_kernel<<<4864, 256, 0, stream>>>(w_qkv, wqkvT, w_out, woutT, timep, mod_w, mod_b, modbuf);
    ln_mod_kernel<<<2048, 256, 0, stream>>>(x, modbuf, hbuf);
    gemm_qkv_mfma<<<dim3(24, 64), 256, 0, stream>>>(hbuf, wqkvT, qbuf, kbuf, vbuf);
    lnrope_kernel<<<16384, 256, 0, stream>>>(qbuf, kbuf, qw, kw, pos);
    attn_mfma_kernel<<<1024, 512, 0, stream>>>(qbuf, kbuf, vbuf, obuf);
    gemm_out_mfma<<<dim3(8, 64), 256, 0, stream>>>(obuf, woutT, modbuf, outp);
}

// Round 24
// 191.424 us; speedup vs baseline: 1.1457x; 1.0033x over previous
//
#include <hip/hip_runtime.h>

typedef short bf16x8 __attribute__((ext_vector_type(8)));
typedef float f32x4 __attribute__((ext_vector_type(4)));

#define LN_EPS 1e-6f
#define QSCALE 0.1803368801111143f   // 0.125 * log2(e)

static __device__ __forceinline__ float bf2f(unsigned short u) {
    union { unsigned int i; float f; } v; v.i = ((unsigned int)u) << 16; return v.f;
}
static __device__ __forceinline__ unsigned short f2bf(float f) {
    union { float ff; unsigned int i; } v; v.ff = f;
    return (unsigned short)((v.i + 0x7FFFu + ((v.i >> 16) & 1u)) >> 16);  // RNE
}
// async global->LDS, 16B per lane; LDS dest is wave-uniform base + lane*16
static __device__ __forceinline__ void gl_lds16(const unsigned short* g, unsigned short* l) {
    __builtin_amdgcn_global_load_lds((__attribute__((address_space(1))) void*)g,
                                     (__attribute__((address_space(3))) void*)l,
                                     16, 0, 0);
}

// ---------------- kernel: fused prep = {transpose w_qkv, transpose w_out, mod} ----------------
// blocks 0..3071: transpose w_qkv; 3072..4095: transpose w_out; 4096..4863: mod (K-split x8).
__global__ __launch_bounds__(256) void prep_kernel(const float* __restrict__ w_qkv,
                                                   unsigned short* __restrict__ wqkvT,
                                                   const float* __restrict__ w_out,
                                                   unsigned short* __restrict__ woutT,
                                                   const float* __restrict__ timep,
                                                   const float* __restrict__ mod_w,
                                                   const float* __restrict__ mod_b,
                                                   float* __restrict__ mod) {
    __shared__ __align__(16) char sm[5248];
    const int bid = blockIdx.x;
    if (bid < 4096) {
        const float* src; unsigned short* dst; int C, c0, r0;
        if (bid < 3072) { src = w_qkv; dst = wqkvT; C = 3072; c0 = (bid % 96) * 32; r0 = (bid / 96) * 32; }
        else { int i2 = bid - 3072; src = w_out; dst = woutT; C = 1024; c0 = (i2 & 31) * 32; r0 = (i2 >> 5) * 32; }
        unsigned short (*t)[33] = (unsigned short(*)[33])sm;
        int tx = threadIdx.x & 31, ty = threadIdx.x >> 5;
        #pragma unroll
        for (int i = 0; i < 4; ++i) {
            int r = ty + i * 8;
            t[r][tx] = f2bf(src[(size_t)(r0 + r) * C + c0 + tx]);
        }
        __syncthreads();
        #pragma unroll
        for (int i = 0; i < 4; ++i) {
            int c = ty + i * 8;
            dst[(size_t)(c0 + c) * 1024 + r0 + tx] = t[tx][c];
        }
    } else {
        const int mb = bid - 4096;                // 0..767
        float* st = (float*)sm;                   // 4096 B
        float (*part)[33] = (float(*)[33])(sm + 4096);
        const int b = mb / 96;
        const int jb = mb % 96;
        const int tid = threadIdx.x;
        const int j = jb * 32 + (tid & 31);
        const int sub = tid >> 5;                 // 0..7, covers k = sub*128..+127
        for (int i = tid; i < 1024; i += 256) {
            float t = timep[b * 1024 + i];
            st[i] = t / (1.0f + __expf(-t));      // silu
        }
        __syncthreads();
        float acc = 0.f;
        const int k0 = sub * 128;
        #pragma unroll 4
        for (int m = 0; m < 128; ++m)
            acc = fmaf(st[k0 + m], mod_w[(size_t)(k0 + m) * 3072 + j], acc);
        part[sub][tid & 31] = acc;
        __syncthreads();
        if (tid < 32) {
            float s = mod_b[jb * 32 + tid];
            #pragma unroll
            for (int p = 0; p < 8; ++p) s += part[p][tid];   // fixed order: deterministic
            mod[b * 3072 + jb * 32 + tid] = s;
        }
    }
}

// ---------------- kernel: h = LN(x) * (scale+1) + shift -> bf16; wave-per-row, no LDS/barriers ----------------
__global__ __launch_bounds__(256) void ln_mod_kernel(const float* __restrict__ x,
                                                     const float* __restrict__ mod,
                                                     unsigned short* __restrict__ h) {
    int row = blockIdx.x * 4 + (threadIdx.x >> 6);   // b*1024 + t
    int lane = threadIdx.x & 63;
    int b = row >> 10;
    const float* xr = x + (size_t)row * 1024;
    float4 v[4];
    float s = 0.f, ss = 0.f;
    #pragma unroll
    for (int j = 0; j < 4; ++j) {
        v[j] = *reinterpret_cast<const float4*>(xr + j * 256 + lane * 4);
        s  += v[j].x + v[j].y + v[j].z + v[j].w;
        ss += v[j].x * v[j].x + v[j].y * v[j].y + v[j].z * v[j].z + v[j].w * v[j].w;
    }
    #pragma unroll
    for (int o = 32; o >= 1; o >>= 1) { s += __shfl_xor(s, o); ss += __shfl_xor(ss, o); }
    float mean = s * (1.0f / 1024.0f);
    float rstd = rsqrtf(ss * (1.0f / 1024.0f) - mean * mean + LN_EPS);
    const float* mb = mod + b * 3072;
    #pragma unroll
    for (int j = 0; j < 4; ++j) {
        int d = j * 256 + lane * 4;
        float4 shf = *reinterpret_cast<const float4*>(mb + d);          // shift
        float4 scl = *reinterpret_cast<const float4*>(mb + 1024 + d);   // scale
        ushort4 o4;
        o4.x = f2bf((v[j].x - mean) * rstd * (scl.x + 1.0f) + shf.x);
        o4.y = f2bf((v[j].y - mean) * rstd * (scl.y + 1.0f) + shf.y);
        o4.z = f2bf((v[j].z - mean) * rstd * (scl.z + 1.0f) + shf.z);
        o4.w = f2bf((v[j].w - mean) * rstd * (scl.w + 1.0f) + shf.w);
        *reinterpret_cast<ushort4*>(h + (size_t)row * 1024 + d) = o4;
    }
}

// ---------------- MFMA GEMM main loop (m97 structure): global_load_lds staging ----------------
static __device__ __forceinline__ void gemm_mainloop(const unsigned short* __restrict__ A,
                                                     const unsigned short* __restrict__ Bt,
                                                     int m0, int n0,
                                                     unsigned short* As, unsigned short* Bs,
                                                     f32x4 (&acc)[4][4]) {
    const int tid = threadIdx.x;
    const int wid = tid >> 6, lane = tid & 63;
    const int wr = wid >> 1, wc = wid & 1;
    const int lr = lane & 15, lks = lane >> 4;
    const int gofs = (lane >> 3) * 1024 + (((lane & 7) ^ (lane >> 3)) * 8);
    const unsigned short* Ag = A  + (size_t)(m0 + wid * 32) * 1024 + gofs;
    const unsigned short* Bg = Bt + (size_t)(n0 + wid * 32) * 1024 + gofs;
    unsigned short* AsW = As + wid * 32 * 64;
    unsigned short* BsW = Bs + wid * 32 * 64;
    for (int k0 = 0; k0 < 1024; k0 += 64) {
        __syncthreads();
        #pragma unroll
        for (int j = 0; j < 4; ++j) {
            gl_lds16(Ag + k0 + j * 8192, AsW + j * 512);
            gl_lds16(Bg + k0 + j * 8192, BsW + j * 512);
        }
        __syncthreads();
        #pragma unroll
        for (int ks = 0; ks < 2; ++ks) {
            bf16x8 af[4], bfr[4];
            #pragma unroll
            for (int mi = 0; mi < 4; ++mi) {
                int row = wr * 64 + mi * 16 + lr;
                int ss = (ks * 4 + lks) ^ (row & 7);
                af[mi] = *reinterpret_cast<const bf16x8*>(As + row * 64 + ss * 8);
            }
            #pragma unroll
            for (int ni = 0; ni < 4; ++ni) {
                int row = wc * 64 + ni * 16 + lr;
                int ss = (ks * 4 + lks) ^ (row & 7);
                bfr[ni] = *reinterpret_cast<const bf16x8*>(Bs + row * 64 + ss * 8);
            }
            #pragma unroll
            for (int mi = 0; mi < 4; ++mi)
                #pragma unroll
                for (int ni = 0; ni < 4; ++ni)
                    acc[mi][ni] = __builtin_amdgcn_mfma_f32_16x16x32_bf16(af[mi], bfr[ni], acc[mi][ni], 0, 0, 0);
        }
    }
}

// ---------------- kernel: qkv GEMM (MFMA); q/k scattered (B,H,T,64); v stored TRANSPOSED (B,H,64,T) ----------------
__global__ __launch_bounds__(256) void gemm_qkv_mfma(const unsigned short* __restrict__ A,
                                                     const unsigned short* __restrict__ Bt,
                                                     unsigned short* __restrict__ qb,
                                                     unsigned short* __restrict__ kb,
                                                     unsigned short* __restrict__ vb) {
    __shared__ __align__(16) unsigned short smem[16640];   // As|Bs (16384), bounce uses stride 130
    unsigned short* As = smem;
    unsigned short* Bs = smem + 8192;
    const int bid = blockIdx.y * 24 + blockIdx.x;
    const int xcd = bid & 7, idx = bid >> 3;
    const int m0 = (xcd * 8 + (idx & 7)) * 128;
    const int n0 = (idx >> 3) * 128;
    const int tid = threadIdx.x;
    const int wid = tid >> 6, lane = tid & 63;
    const int wr = wid >> 1, wc = wid & 1;
    const int lr = lane & 15, g = lane >> 4;
    const int which = n0 >> 10;                     // block-uniform: 0=q 1=k 2=v
    f32x4 acc[4][4] = {};
    gemm_mainloop(A, Bt, m0, n0, As, Bs, acc);
    __syncthreads();
    // ---- bounce C tile to LDS (stride 130); v blocks bounce TRANSPOSED ----
    #pragma unroll
    for (int mi = 0; mi < 4; ++mi)
    #pragma unroll
    for (int ni = 0; ni < 4; ++ni)
    #pragma unroll
    for (int r = 0; r < 4; ++r) {
        int row = wr * 64 + mi * 16 + g * 4 + r;
        int col = wc * 64 + ni * 16 + lr;
        if (which == 2) smem[col * 130 + row] = f2bf(acc[mi][ni][r]);
        else            smem[row * 130 + col] = f2bf(acc[mi][ni][r]);
    }
    __syncthreads();
    const int bb = m0 >> 10, tbase = m0 & 1023;
    if (which == 2) {
        // transposed store: 16B along t
        #pragma unroll
        for (int p = 0; p < 8; ++p) {
            int seg = (tid >> 3) + p * 32;          // 0..255
            int erow = seg >> 1, half = seg & 1, sub = tid & 7;
            int4 v = *reinterpret_cast<const int4*>(smem + erow * 130 + half * 64 + sub * 8);
            int eg = (n0 & 1023) + erow;
            int hd = eg >> 6, ei = eg & 63;
            *reinterpret_cast<int4*>(vb + (((size_t)(bb * 16 + hd) * 64 + ei) << 10)
                                        + tbase + half * 64 + sub * 8) = v;
        }
    } else {
        unsigned short* dst = which == 0 ? qb : kb;
        #pragma unroll
        for (int p = 0; p < 8; ++p) {
            int seg = (tid >> 3) + p * 32;
            int row = seg >> 1, half = seg & 1, sub = tid & 7;
            int4 v = *reinterpret_cast<const int4*>(smem + row * 130 + half * 64 + sub * 8);
            int colb = n0 + half * 64;
            int hd = (colb & 1023) >> 6;
            int t = tbase + row;
            *reinterpret_cast<int4*>(dst + (((size_t)(bb * 16 + hd) * 1024 + t) << 6) + sub * 8) = v;
        }
    }
}

// ---------------- kernel: out GEMM (MFMA), 2-pass f32 LDS-bounce, fused gate ----------------
__global__ __launch_bounds__(256) void gemm_out_mfma(const unsigned short* __restrict__ A,
                                                     const unsigned short* __restrict__ Bt,
                                                     const float* __restrict__ mod,
                                                     float* __restrict__ out) {
    __shared__ __align__(16) unsigned short smem[16640];
    unsigned short* As = smem;
    unsigned short* Bs = smem + 8192;
    float* fsm = reinterpret_cast<float*>(smem);           // [64][128] f32 = 32 KB
    const int bid = blockIdx.y * 8 + blockIdx.x;
    const int xcd = bid & 7, idx = bid >> 3;
    const int m0 = (xcd * 8 + (idx & 7)) * 128;
    const int n0 = (idx >> 3) * 128;
    const int tid = threadIdx.x;
    const int wid = tid >> 6, lane = tid & 63;
    const int wr = wid >> 1, wc = wid & 1;
    const int lr = lane & 15, g = lane >> 4;
    f32x4 acc[4][4] = {};
    gemm_mainloop(A, Bt, m0, n0, As, Bs, acc);
    #pragma unroll
    for (int hp = 0; hp < 2; ++hp) {
        __syncthreads();
        if (wr == hp) {
            #pragma unroll
            for (int mi = 0; mi < 4; ++mi)
            #pragma unroll
            for (int ni = 0; ni < 4; ++ni)
            #pragma unroll
            for (int r = 0; r < 4; ++r)
                fsm[(mi * 16 + g * 4 + r) * 128 + wc * 64 + ni * 16 + lr] = acc[mi][ni][r];
        }
        __syncthreads();
        #pragma unroll
        for (int p = 0; p < 8; ++p) {
            int unit = tid + p * 256;
            int lrow = unit >> 5, sub = unit & 31;
            float4 v = *reinterpret_cast<const float4*>(fsm + lrow * 128 + sub * 4);
            int row = m0 + hp * 64 + lrow;
            int col = n0 + sub * 4;
            int bb = row >> 10;
            float4 gv = *reinterpret_cast<const float4*>(mod + bb * 3072 + 2048 + col);
            float4 o4;
            o4.x = v.x * gv.x; o4.y = v.y * gv.y; o4.z = v.z * gv.z; o4.w = v.w * gv.w;
            *reinterpret_cast<float4*>(out + (size_t)row * 1024 + col) = o4;
        }
    }
}

// ---------------- kernel: per-row (e=64) LN + RoPE, 4 rows/wave vectorized ----------------
__global__ __launch_bounds__(256) void lnrope_kernel(unsigned short* __restrict__ qb,
                                                     unsigned short* __restrict__ kb,
                                                     const float* __restrict__ qw,
                                                     const float* __restrict__ kw,
                                                     const float* __restrict__ pos) {
    int gw = blockIdx.x * 4 + (threadIdx.x >> 6);   // wave id 0..65535
    int lane = threadIdx.x & 63;
    int half = gw >> 15;                            // 0 = q, 1 = k
    int rw = (gw * 4 + (lane >> 4)) & 131071;       // row within buffer
    unsigned short* buf = half ? kb : qb;
    const float* w = half ? kw : qw;
    int t = rw & 1023;
    int c4 = (lane & 15) * 4;                       // element base 0..60
    size_t idx = (size_t)rw * 64 + c4;
    ushort4 u = *reinterpret_cast<const ushort4*>(buf + idx);
    float f0 = bf2f(u.x), f1 = bf2f(u.y), f2 = bf2f(u.z), f3 = bf2f(u.w);
    float s1 = f0 + f1 + f2 + f3;
    float s2 = f0 * f0 + f1 * f1 + f2 * f2 + f3 * f3;
    #pragma unroll
    for (int o = 1; o <= 8; o <<= 1) { s1 += __shfl_xor(s1, o); s2 += __shfl_xor(s2, o); }
    float mean = s1 * (1.0f / 64.0f);
    float rstd = rsqrtf(s2 * (1.0f / 64.0f) - mean * mean + LN_EPS);
    float4 wv = *reinterpret_cast<const float4*>(w + c4);
    float y0 = (f0 - mean) * rstd * wv.x;
    float y1 = (f1 - mean) * rstd * wv.y;
    float y2 = (f2 - mean) * rstd * wv.z;
    float y3 = (f3 - mean) * rstd * wv.w;
    if (c4 < 32) {   // rotated half; pairs (y0,y1),(y2,y3) in-lane
        float4 p = *reinterpret_cast<const float4*>(pos + t * 32 + c4);
        float a;
        a = y0; y0 = a * p.x - y1 * p.y; y1 = y1 * p.x + a * p.y;
        a = y2; y2 = a * p.z - y3 * p.w; y3 = y3 * p.z + a * p.w;
    }
    const float SC = half ? 1.0f : QSCALE;          // q: fold 1/8 and log2e (softmax uses exp2)
    ushort4 o;
    o.x = f2bf(y0 * SC); o.y = f2bf(y1 * SC); o.z = f2bf(y2 * SC); o.w = f2bf(y3 * SC);
    *reinterpret_cast<ushort4*>(buf + idx) = o;
}

// ---------------- kernel: MFMA flash attention v10 (QBLK=128, 8 waves, Q direct from global) ----------------
// KVBLK=64, no-max exp2 softmax, double-buffered K/V via global_load_lds.
// Q fragments loaded directly from global (natural layout == fragment layout): no Q LDS
// stage, one prologue barrier. 48 KB LDS -> 3 blocks/CU x 8 waves = 24 waves/CU.
__global__ __launch_bounds__(512) void attn_mfma_kernel(const unsigned short* __restrict__ qb,
                                                        const unsigned short* __restrict__ kb,
                                                        const unsigned short* __restrict__ vt,
                                                        unsigned short* __restrict__ ob) {
    __shared__ __align__(16) unsigned char smem[49152];
    unsigned short* KsB = (unsigned short*)smem;            // 2 x [64 kv][64 d]   (2 x 8 KB)
    unsigned short* VsB = (unsigned short*)(smem + 16384);  // 2 x [64 d][64 kv]   (2 x 8 KB)
    unsigned short* paB = (unsigned short*)(smem + 32768);  // pa[8 waves][16][64] (16 KB)

    const int bid = blockIdx.x;                             // 0..1023
    const int swz = (bid & 7) * 128 + (bid >> 3);           // XCD-chunked
    const int bh = swz >> 3;                                // 0..127
    const int q0 = (swz & 7) * 128;                         // 0..896
    const int b = bh >> 4, hd = bh & 15;
    const size_t base = (size_t)bh << 16;                   // bh * 1024 * 64
    const int tid = threadIdx.x, wid = tid >> 6, lane = tid & 63;
    const int lr = lane & 15, g = lane >> 4;

    // ---- precomputed swizzled LDS offsets (loop-invariant; live in VGPRs) ----
    int kRd[2][4], pRd[2], pwOff[4][4];
    #pragma unroll
    for (int ks = 0; ks < 2; ++ks) {
        pRd[ks] = lr * 64 + (((ks * 4 + g) ^ (lr & 7)) * 8);
        #pragma unroll
        for (int nt = 0; nt < 4; ++nt)
            kRd[ks][nt] = (nt * 16 + lr) * 64 + (((ks * 4 + g) ^ (lr & 7)) * 8);
    }
    #pragma unroll
    for (int nt = 0; nt < 4; ++nt)
    #pragma unroll
    for (int r = 0; r < 4; ++r) {
        int q = g * 4 + r;
        pwOff[nt][r] = q * 64 + (((nt * 2 + (lr >> 3)) ^ (q & 7)) * 8) + (lr & 7);
    }

    // per-lane pre-swizzled global source pointers for K/V staging
    // 512 threads x 16B = 8 KB = one full chunk per issue
    const int sr = tid >> 3, ssg = tid & 7;
    const unsigned short* kSrc = kb + base + (size_t)sr * 64 + ((ssg ^ (sr & 7)) * 8);
    const unsigned short* vSrc = vt + base + (size_t)sr * 1024 + ((ssg ^ (sr & 7)) * 8);

    // ---- prologue: stage chunk 0 (buf 0); Q fragments direct from global ----
    gl_lds16(kSrc, KsB + wid * 512);
    gl_lds16(vSrc, VsB + wid * 512);
    bf16x8 af[2];
    {
        int row = q0 + wid * 16 + lr;
        af[0] = *reinterpret_cast<const bf16x8*>(qb + base + (size_t)row * 64 + (g) * 8);
        af[1] = *reinterpret_cast<const bf16x8*>(qb + base + (size_t)row * 64 + (4 + g) * 8);
    }
    __syncthreads();   // drains chunk-0 gl_lds (vmcnt) before first compute

    f32x4 acc[4] = {};
    float l_par[4] = {0.f, 0.f, 0.f, 0.f};     // lane-partial denominators
    unsigned short* pa_w = paB + wid * 1024;   // wave-private P [16 q][64 kv] swizzled
    const f32x4 zero4 = {0.f, 0.f, 0.f, 0.f};

    for (int cc = 0; cc < 16; ++cc) {
        const int cur = cc & 1;
        // ---- issue async prefetch of chunk cc+1 into the other buffer ----
        if (cc < 15) {
            const int kv1 = (cc + 1) * 64;
            gl_lds16(kSrc + (size_t)kv1 * 64, KsB + (cur ^ 1) * 4096 + wid * 512);
            gl_lds16(vSrc + kv1,              VsB + (cur ^ 1) * 4096 + wid * 512);
        }
        const unsigned short* Kc = KsB + cur * 4096;
        const unsigned short* Vc = VsB + cur * 4096;
        // ---- QK^T: S[16 q][64 kv] per wave (8 MFMAs); first ks uses C=0 ----
        f32x4 s[4];
        __builtin_amdgcn_s_setprio(1);
        #pragma unroll
        for (int nt = 0; nt < 4; ++nt) {
            bf16x8 kf = *reinterpret_cast<const bf16x8*>(Kc + kRd[0][nt]);
            s[nt] = __builtin_amdgcn_mfma_f32_16x16x32_bf16(af[0], kf, zero4, 0, 0, 0);
        }
        #pragma unroll
        for (int nt = 0; nt < 4; ++nt) {
            bf16x8 kf = *reinterpret_cast<const bf16x8*>(Kc + kRd[1][nt]);
            s[nt] = __builtin_amdgcn_mfma_f32_16x16x32_bf16(af[1], kf, s[nt], 0, 0, 0);
        }
        __builtin_amdgcn_s_setprio(0);
        // ---- no-max softmax: P = exp2(s), lane-partial l ----
        #pragma unroll
        for (int r = 0; r < 4; ++r)
        #pragma unroll
        for (int nt = 0; nt < 4; ++nt) {
            float e = exp2f(s[nt][r]);
            s[nt][r] = e;
            l_par[r] += e;
        }
        // ---- write P (bf16) to wave-private LDS in A-fragment layout ----
        #pragma unroll
        for (int nt = 0; nt < 4; ++nt)
        #pragma unroll
        for (int r = 0; r < 4; ++r) {
            unsigned int pk;
            asm("v_cvt_pk_bf16_f32 %0, %1, %2" : "=v"(pk) : "v"(s[nt][r]), "v"(0.f));
            pa_w[pwOff[nt][r]] = (unsigned short)pk;
        }
        // ---- PV: O += P @ V (8 MFMAs) ----
        __builtin_amdgcn_s_setprio(1);
        #pragma unroll
        for (int ks = 0; ks < 2; ++ks) {
            bf16x8 paf = *reinterpret_cast<const bf16x8*>(pa_w + pRd[ks]);
            #pragma unroll
            for (int nt = 0; nt < 4; ++nt) {
                bf16x8 vf = *reinterpret_cast<const bf16x8*>(Vc + kRd[ks][nt]);
                acc[nt] = __builtin_amdgcn_mfma_f32_16x16x32_bf16(paf, vf, acc[nt], 0, 0, 0);
            }
        }
        __builtin_amdgcn_s_setprio(0);
        // one barrier: all reads of buf[cur] done (next iter overwrites it) AND
        // drains vmcnt so the cc+1 prefetch is visible for the next iteration.
        __syncthreads();
    }
    // ---- final: reduce lane-partial l, O/l, write (B, T, H*64) ----
    float inv[4];
    #pragma unroll
    for (int r = 0; r < 4; ++r) {
        float l = l_par[r];
        #pragma unroll
        for (int o = 1; o <= 8; o <<= 1) l += __shfl_xor(l, o);
        inv[r] = 1.0f / l;
    }
    #pragma unroll
    for (int nt = 0; nt < 4; ++nt)
    #pragma unroll
    for (int r = 0; r < 4; ++r) {
        int q = q0 + wid * 16 + g * 4 + r;
        int d = hd * 64 + nt * 16 + lr;
        ob[(size_t)(b * 1024 + q) * 1024 + d] = f2bf(acc[nt][r] * inv[r]);
    }
}

extern "C" void kernel_launch(void* const* d_in, const int* in_sizes, int n_in,
                              void* d_out, int out_size, void* d_ws, size_t ws_size,
                              hipStream_t stream) {
    const float* x      = (const float*)d_in[0];
    const float* timep  = (const float*)d_in[1];
    const float* pos    = (const float*)d_in[2];
    const float* mod_w  = (const float*)d_in[3];
    const float* mod_b  = (const float*)d_in[4];
    const float* w_qkv  = (const float*)d_in[5];
    const float* w_out  = (const float*)d_in[6];
    const float* qw     = (const float*)d_in[7];
    const float* kw     = (const float*)d_in[8];
    float* outp = (float*)d_out;                   // f32 (8,1024,1024)

    char* ws = (char*)d_ws;
    float*          modbuf = (float*)ws;                          // 98304 B
    unsigned short* wqkvT  = (unsigned short*)(ws + 98304);       // bf16 [3072][1024]
    unsigned short* woutT  = (unsigned short*)(ws + 6389760);     // bf16 [1024][1024]
    unsigned short* hbuf   = (unsigned short*)(ws + 8486912);     // 16 MB (h, then o)
    unsigned short* qbuf   = hbuf + 8388608;
    unsigned short* kbuf   = qbuf + 8388608;
    unsigned short* vbuf   = kbuf + 8388608;       // v in (B,H,64,T) layout
    unsigned short* obuf   = hbuf;

    prep_kernel<<<4864, 256, 0, stream>>>(w_qkv, wqkvT, w_out, woutT, timep, mod_w, mod_b, modbuf);
    ln_mod_kernel<<<2048, 256, 0, stream>>>(x, modbuf, hbuf);
    gemm_qkv_mfma<<<dim3(24, 64), 256, 0, stream>>>(hbuf, wqkvT, qbuf, kbuf, vbuf);
    lnrope_kernel<<<16384, 256, 0, stream>>>(qbuf, kbuf, qw, kw, pos);
    attn_mfma_kernel<<<1024, 512, 0, stream>>>(qbuf, kbuf, vbuf, obuf);
    gemm_out_mfma<<<dim3(8, 64), 256, 0, stream>>>(obuf, woutT, modbuf, outp);
}